// Round 2
// baseline (6615.470 us; speedup 1.0000x reference)
//
#include <hip/hip_runtime.h>
#include <math.h>

// ---------------------------------------------------------------------------
// TACE (MACE-style equivariant GNN) forward on MI355X.
// N=5000 nodes, E=80000 edges, C=64, 2 layers, ranks 0..3 (dims 1,3,9,27).
//
// R2 restructure:
//  - k_radial_mlp computes R[l,e,256] for BOTH layers in ONE dispatch
//    (radial MLP is independent of h0). Each 64-edge group is handled by
//    2 waves (rank-halves) -> 5000 waves total vs 1250 before.
//  - t = R * h0[sender] fused into k_node (no tbuf round-trip).
// ---------------------------------------------------------------------------

#define PI_F 3.14159265358979323846f

__device__ __forceinline__ float silu_f(float x) {
    return x / (1.0f + expf(-x));
}

// ---------------- edge basis + angular ----------------
__global__ void k_edge_basis(const float* __restrict__ ev,
                             float* __restrict__ rb,
                             float* __restrict__ Yb, int E)
{
    int e = blockIdx.x * blockDim.x + threadIdx.x;
    if (e >= E) return;
    float vx = ev[3*e+0], vy = ev[3*e+1], vz = ev[3*e+2];
    float r2 = vx*vx + vy*vy + vz*vz + 1e-12f;
    float r  = sqrtf(r2);
    float x  = r * 0.2f;                   // r / CUTOFF
    float x2 = x*x;
    float x5 = x2*x2*x;
    // env = 1 - 21 x^5 + 35 x^6 - 15 x^7   (P=5)
    float env = 1.0f + x5*(-21.0f + x*(35.0f - 15.0f*x));
    if (x >= 1.0f) env = 0.0f;
    float pref = 0.632455532033675866f / r * env;   // sqrt(2/5)/r * env
    float pix  = PI_F * x;
    float* rbp = rb + (size_t)e*8;
    #pragma unroll
    for (int k = 0; k < 8; ++k) rbp[k] = pref * sinf((float)(k+1) * pix);

    float ir = 1.0f / r;
    float hv[3];
    hv[0] = vx*ir; hv[1] = vy*ir; hv[2] = vz*ir;
    float* Yr = Yb + (size_t)e*40;
    const float s3 = 1.73205080756887729f;
    const float s5 = 2.23606797749978969f;
    const float s7 = 2.64575131106459059f;
    Yr[0] = 1.0f;
    #pragma unroll
    for (int i = 0; i < 3; ++i) Yr[1+i] = s3*hv[i];
    #pragma unroll
    for (int i = 0; i < 3; ++i)
        #pragma unroll
        for (int j = 0; j < 3; ++j) Yr[4+i*3+j] = s5*hv[i]*hv[j];
    #pragma unroll
    for (int i = 0; i < 3; ++i)
        #pragma unroll
        for (int j = 0; j < 3; ++j)
            #pragma unroll
            for (int k = 0; k < 3; ++k) Yr[13+i*9+j*3+k] = s7*hv[i]*hv[j]*hv[k];
}

// ---------------- CSR build ----------------
__global__ void k_hist(const int* __restrict__ recv, int* __restrict__ counts, int E)
{
    int e = blockIdx.x * blockDim.x + threadIdx.x;
    if (e < E) atomicAdd(&counts[recv[e]], 1);
}

__global__ void k_scan(const int* __restrict__ counts, int* __restrict__ offsets, int N)
{
    __shared__ int lds[1024];
    __shared__ int basev;
    if (threadIdx.x == 0) basev = 0;
    __syncthreads();
    for (int start = 0; start < N; start += 1024) {
        int i = start + (int)threadIdx.x;
        int v = (i < N) ? counts[i] : 0;
        lds[threadIdx.x] = v;
        __syncthreads();
        for (int off = 1; off < 1024; off <<= 1) {
            int add = (threadIdx.x >= (unsigned)off) ? lds[threadIdx.x - off] : 0;
            __syncthreads();
            lds[threadIdx.x] += add;
            __syncthreads();
        }
        if (i < N) offsets[i] = basev + lds[threadIdx.x] - v;  // exclusive
        __syncthreads();
        if (threadIdx.x == 1023) basev += lds[1023];
        __syncthreads();
    }
    if (threadIdx.x == 0) offsets[N] = basev;
}

__global__ void k_scatter(const int* __restrict__ recv,
                          const int* __restrict__ offsets,
                          int* __restrict__ cursor,
                          int* __restrict__ elist, int E)
{
    int e = blockIdx.x * blockDim.x + threadIdx.x;
    if (e >= E) return;
    int r = recv[e];
    int p = atomicAdd(&cursor[r], 1);
    elist[offsets[r] + p] = e;
}

__global__ void k_sort(const int* __restrict__ offsets, int* __restrict__ elist, int N)
{
    int n = blockIdx.x * blockDim.x + threadIdx.x;
    if (n >= N) return;
    int b = offsets[n], e2 = offsets[n+1];
    for (int i = b + 1; i < e2; ++i) {
        int v = elist[i];
        int j = i - 1;
        while (j >= b && elist[j] > v) { elist[j+1] = elist[j]; --j; }
        elist[j+1] = v;
    }
}

__global__ void k_embed(const int* __restrict__ species,
                        const float* __restrict__ embw,
                        float* __restrict__ h0, int NC)
{
    int i = blockIdx.x * blockDim.x + threadIdx.x;
    if (i >= NC) return;
    int n = i >> 6, c = i & 63;
    h0[i] = embw[species[n]*64 + c];
}

// ---------------- radial MLP (both layers, rank-split) ----------------
// wave wid -> (layer l, edge-group g, rank-half). Lane = edge within group.
// Hidden state in registers; weights wave-uniform -> scalar-operand FMAs.
// 5000 waves total (nl=2): ~4x the parallelism of the R1 version.
__global__ __launch_bounds__(256) void k_radial_mlp(
    const float* __restrict__ rb,       // [E,8]
    const float* __restrict__ rw1,      // [L,8,64]
    const float* __restrict__ rw2,      // [L,64,64]
    const float* __restrict__ rw3,      // [L,64,64]
    const float* __restrict__ rw4,      // [L,64,256]
    float* __restrict__ Rbuf,           // [nl,E,256]
    int lbase, int nl, int E, int ngroups)
{
    __shared__ float xch[4][64][17];    // per-wave chunked transpose buffer
    int lane = threadIdx.x & 63;
    int w    = threadIdx.x >> 6;
    int wid  = blockIdx.x * 4 + w;
    int total = nl * ngroups * 2;
    bool wval = (wid < total);
    int widc = wval ? wid : 0;
    int l    = widc / (ngroups * 2);
    int rem  = widc % (ngroups * 2);
    int g    = rem >> 1;
    int half = rem & 1;
    int layer = lbase + l;

    const float* w1 = rw1 + (size_t)layer * 8 * 64;
    const float* w2 = rw2 + (size_t)layer * 64 * 64;
    const float* w3 = rw3 + (size_t)layer * 64 * 64;
    const float* w4 = rw4 + (size_t)layer * 64 * 256;

    int e = g * 64 + lane;
    bool val = wval && (e < E);

    float rbv[8];
    #pragma unroll
    for (int k = 0; k < 8; ++k) rbv[k] = val ? rb[(size_t)e*8 + k] : 0.0f;

    float ha[64], hb[64];
    // stage 1: ha = silu(rb @ w1)
    #pragma unroll
    for (int c = 0; c < 64; ++c) ha[c] = 0.0f;
    #pragma unroll
    for (int k = 0; k < 8; ++k) {
        float v = rbv[k];
        #pragma unroll
        for (int c = 0; c < 64; ++c) ha[c] = fmaf(v, w1[k*64 + c], ha[c]);
    }
    #pragma unroll
    for (int c = 0; c < 64; ++c) ha[c] = silu_f(ha[c]);

    // stage 2: hb = silu(ha @ w2)
    #pragma unroll
    for (int c = 0; c < 64; ++c) hb[c] = 0.0f;
    #pragma unroll
    for (int j = 0; j < 64; ++j) {
        float v = ha[j];
        #pragma unroll
        for (int c = 0; c < 64; ++c) hb[c] = fmaf(v, w2[j*64 + c], hb[c]);
    }
    #pragma unroll
    for (int c = 0; c < 64; ++c) hb[c] = silu_f(hb[c]);

    // stage 3: ha = silu(hb @ w3)
    #pragma unroll
    for (int c = 0; c < 64; ++c) ha[c] = 0.0f;
    #pragma unroll
    for (int j = 0; j < 64; ++j) {
        float v = hb[j];
        #pragma unroll
        for (int c = 0; c < 64; ++c) ha[c] = fmaf(v, w3[j*64 + c], ha[c]);
    }
    #pragma unroll
    for (int c = 0; c < 64; ++c) ha[c] = silu_f(ha[c]);

    // stage 4: my 2 ranks of R = ha @ w4, transposed store via small LDS tiles
    for (int rr = 0; rr < 2; ++rr) {
        int ri = half * 2 + rr;
        float acc[64];
        #pragma unroll
        for (int c = 0; c < 64; ++c) acc[c] = 0.0f;
        #pragma unroll
        for (int j = 0; j < 64; ++j) {
            float v = ha[j];
            #pragma unroll
            for (int c = 0; c < 64; ++c)
                acc[c] = fmaf(v, w4[j*256 + ri*64 + c], acc[c]);
        }
        // chunked 64x16 transpose: write my edge's 16 channels, read 4 edges x 16ch
        for (int ch = 0; ch < 4; ++ch) {
            #pragma unroll
            for (int cc = 0; cc < 16; ++cc) xch[w][lane][cc] = acc[ch*16 + cc];
            __syncthreads();
            int et0 = lane >> 4;
            int cid = lane & 15;
            int c   = ch*16 + cid;
            #pragma unroll
            for (int it = 0; it < 16; ++it) {
                int et = it*4 + et0;
                int e2 = g*64 + et;
                if (wval && e2 < E)
                    Rbuf[((size_t)l*E + e2)*256 + ri*64 + c] = xch[w][et][cid];
            }
            __syncthreads();
        }
    }
}

// ---------------- node gather + contraction + mix + readout ----------------
__global__ __launch_bounds__(256) void k_node(
    const float* __restrict__ Rbuf,    // [E,256] this layer
    const float* __restrict__ h0,      // [N,64] input features
    const int*   __restrict__ senders, // [E]
    const float* __restrict__ Yb,      // [E,40]
    const int*   __restrict__ offsets, // [N+1]
    const int*   __restrict__ elist,   // [E]
    const float* __restrict__ mixw,    // [4,64,64] (this layer)
    const float* __restrict__ readw,   // [64]      (this layer)
    float* __restrict__ h0n,           // [N,64]
    const float* __restrict__ eprev,   // [N] or null
    float* __restrict__ eout,          // [N]
    int N)
{
    int gtid = blockIdx.x * blockDim.x + threadIdx.x;
    int wave = gtid >> 6;
    int lane = threadIdx.x & 63;
    int w    = threadIdx.x >> 6;
    __shared__ float Bl[4][4][64];
    bool active = (wave < N);
    int n = active ? wave : 0;

    float A[40];
    #pragma unroll
    for (int d = 0; d < 40; ++d) A[d] = 0.0f;

    if (active) {
        int beg = offsets[n], end = offsets[n+1];
        for (int i = beg; i < end; ++i) {
            int e = elist[i];
            int snd = senders[e];
            const float* Yr = Yb + (size_t)e*40;
            const float* Rr = Rbuf + (size_t)e*256;
            float hj = h0[(size_t)snd*64 + lane];
            float t0 = Rr[lane]       * hj;
            float t1 = Rr[64 + lane]  * hj;
            float t2 = Rr[128 + lane] * hj;
            float t3 = Rr[192 + lane] * hj;
            A[0] = fmaf(t0, Yr[0], A[0]);
            #pragma unroll
            for (int d = 0; d < 3; ++d)  A[1+d]  = fmaf(t1, Yr[1+d],  A[1+d]);
            #pragma unroll
            for (int d = 0; d < 9; ++d)  A[4+d]  = fmaf(t2, Yr[4+d],  A[4+d]);
            #pragma unroll
            for (int d = 0; d < 27; ++d) A[13+d] = fmaf(t3, Yr[13+d], A[13+d]);
        }
    }
    const float inv = 1.0f / 16.0f;  // AVG_NEIGH
    #pragma unroll
    for (int d = 0; d < 40; ++d) A[d] *= inv;

    float B0 = A[0];
    float B1 = 0.f, B2 = 0.f, B3 = 0.f;
    #pragma unroll
    for (int d = 0; d < 3; ++d)  B1 = fmaf(A[1+d],  A[1+d],  B1);
    #pragma unroll
    for (int d = 0; d < 9; ++d)  B2 = fmaf(A[4+d],  A[4+d],  B2);
    #pragma unroll
    for (int d = 0; d < 27; ++d) B3 = fmaf(A[13+d], A[13+d], B3);

    Bl[w][0][lane] = B0;
    Bl[w][1][lane] = B1;
    Bl[w][2][lane] = B2;
    Bl[w][3][lane] = B3;
    __syncthreads();

    if (active) {
        float acc = 0.0f;
        for (int ri = 0; ri < 4; ++ri) {
            #pragma unroll 8
            for (int j = 0; j < 64; ++j)
                acc = fmaf(Bl[w][ri][j], mixw[(ri*64 + j)*64 + lane], acc);
        }
        h0n[(size_t)n*64 + lane] = acc;

        float evl = acc * readw[lane];
        #pragma unroll
        for (int off = 1; off < 64; off <<= 1) evl += __shfl_xor(evl, off, 64);
        if (lane == 0) {
            float o = evl;
            if (eprev) o += eprev[n];
            eout[n] = o;
        }
    }
}

// ---------------------------------------------------------------------------
extern "C" void kernel_launch(void* const* d_in, const int* in_sizes, int n_in,
                              void* d_out, int out_size, void* d_ws, size_t ws_size,
                              hipStream_t stream)
{
    const int*   species   = (const int*)  d_in[0];
    const int*   senders   = (const int*)  d_in[1];
    const int*   receivers = (const int*)  d_in[2];
    const float* edge_vec  = (const float*)d_in[3];
    const float* embed_w   = (const float*)d_in[4];
    const float* rad_w1    = (const float*)d_in[5];
    const float* rad_w2    = (const float*)d_in[6];
    const float* rad_w3    = (const float*)d_in[7];
    const float* rad_w4    = (const float*)d_in[8];
    const float* mix_w     = (const float*)d_in[9];
    const float* read_w    = (const float*)d_in[10];

    int N = in_sizes[0];
    int E = in_sizes[1];
    float* out = (float*)d_out;

    char* ws = (char*)d_ws;
    size_t off = 0;
    auto alloc = [&](size_t bytes) -> char* {
        char* p = ws + off;
        off = (off + bytes + 255) & ~(size_t)255;
        return p;
    };
    float* rb    = (float*)alloc((size_t)E*8*sizeof(float));
    float* Yb    = (float*)alloc((size_t)E*40*sizeof(float));
    float* h0a   = (float*)alloc((size_t)N*64*sizeof(float));
    float* h0b   = (float*)alloc((size_t)N*64*sizeof(float));
    float* ener  = (float*)alloc((size_t)N*sizeof(float));
    int* counts  = (int*)alloc((size_t)N*sizeof(int));
    int* offsets = (int*)alloc((size_t)(N+1)*sizeof(int));
    int* cursor  = (int*)alloc((size_t)N*sizeof(int));
    int* elist   = (int*)alloc((size_t)E*sizeof(int));

    // R buffer: both layers if workspace allows, else one layer at a time
    size_t rone = (size_t)E*256*sizeof(float);
    int nl = (off + 2*rone <= ws_size) ? 2 : 1;
    float* Rbuf = (float*)alloc((size_t)nl*rone);

    int ngroups = (E + 63) / 64;

    hipMemsetAsync(counts, 0, (size_t)N*sizeof(int), stream);
    hipMemsetAsync(cursor, 0, (size_t)N*sizeof(int), stream);

    k_edge_basis<<<(E + 255)/256, 256, 0, stream>>>(edge_vec, rb, Yb, E);
    k_hist<<<(E + 255)/256, 256, 0, stream>>>(receivers, counts, E);
    k_scan<<<1, 1024, 0, stream>>>(counts, offsets, N);
    k_scatter<<<(E + 255)/256, 256, 0, stream>>>(receivers, offsets, cursor, elist, E);
    k_sort<<<(N + 255)/256, 256, 0, stream>>>(offsets, elist, N);
    k_embed<<<((size_t)N*64 + 255)/256, 256, 0, stream>>>(species, embed_w, h0a, N*64);

    if (nl == 2) {
        int waves = 2 * ngroups * 2;
        k_radial_mlp<<<(waves + 3)/4, 256, 0, stream>>>(
            rb, rad_w1, rad_w2, rad_w3, rad_w4, Rbuf, 0, 2, E, ngroups);
    }

    float* hcur = h0a;
    float* hnxt = h0b;
    for (int l = 0; l < 2; ++l) {
        float* Rl = Rbuf;
        if (nl == 2) {
            Rl = Rbuf + (size_t)l * E * 256;
        } else {
            int waves = ngroups * 2;
            k_radial_mlp<<<(waves + 3)/4, 256, 0, stream>>>(
                rb, rad_w1, rad_w2, rad_w3, rad_w4, Rbuf, l, 1, E, ngroups);
        }
        k_node<<<((size_t)N*64 + 255)/256, 256, 0, stream>>>(
            Rl, hcur, senders, Yb, offsets, elist,
            mix_w + (size_t)l*4*64*64,
            read_w + (size_t)l*64,
            hnxt,
            (l == 0) ? nullptr : ener,
            (l == 0) ? ener : out,
            N);
        float* tmp = hcur; hcur = hnxt; hnxt = tmp;
    }
}

// Round 3
// 1254.772 us; speedup vs baseline: 5.2722x; 5.2722x over previous
//
#include <hip/hip_runtime.h>
#include <math.h>

// ---------------------------------------------------------------------------
// TACE (MACE-style equivariant GNN) forward on MI355X.
// N=5000 nodes, E=80000 edges, C=64, 2 layers, ranks 0..3 (dims 1,3,9,27).
//
// R3: radial MLP for both layers in one dispatch, 5000 SINGLE-WAVE blocks
// (layer x 64-edge-group x rank-half). Spill-free: acc chunks are fully
// dumped to LDS before each barrier (no reg array live across barriers
// beyond ha[64] + 32 acc regs). t = R * h0[sender] stays fused in k_node.
// ---------------------------------------------------------------------------

#define PI_F 3.14159265358979323846f

__device__ __forceinline__ float silu_f(float x) {
    return x / (1.0f + expf(-x));
}

// ---------------- edge basis + angular ----------------
__global__ void k_edge_basis(const float* __restrict__ ev,
                             float* __restrict__ rb,
                             float* __restrict__ Yb, int E)
{
    int e = blockIdx.x * blockDim.x + threadIdx.x;
    if (e >= E) return;
    float vx = ev[3*e+0], vy = ev[3*e+1], vz = ev[3*e+2];
    float r2 = vx*vx + vy*vy + vz*vz + 1e-12f;
    float r  = sqrtf(r2);
    float x  = r * 0.2f;                   // r / CUTOFF
    float x2 = x*x;
    float x5 = x2*x2*x;
    // env = 1 - 21 x^5 + 35 x^6 - 15 x^7   (P=5)
    float env = 1.0f + x5*(-21.0f + x*(35.0f - 15.0f*x));
    if (x >= 1.0f) env = 0.0f;
    float pref = 0.632455532033675866f / r * env;   // sqrt(2/5)/r * env
    float pix  = PI_F * x;
    float* rbp = rb + (size_t)e*8;
    #pragma unroll
    for (int k = 0; k < 8; ++k) rbp[k] = pref * sinf((float)(k+1) * pix);

    float ir = 1.0f / r;
    float hv[3];
    hv[0] = vx*ir; hv[1] = vy*ir; hv[2] = vz*ir;
    float* Yr = Yb + (size_t)e*40;
    const float s3 = 1.73205080756887729f;
    const float s5 = 2.23606797749978969f;
    const float s7 = 2.64575131106459059f;
    Yr[0] = 1.0f;
    #pragma unroll
    for (int i = 0; i < 3; ++i) Yr[1+i] = s3*hv[i];
    #pragma unroll
    for (int i = 0; i < 3; ++i)
        #pragma unroll
        for (int j = 0; j < 3; ++j) Yr[4+i*3+j] = s5*hv[i]*hv[j];
    #pragma unroll
    for (int i = 0; i < 3; ++i)
        #pragma unroll
        for (int j = 0; j < 3; ++j)
            #pragma unroll
            for (int k = 0; k < 3; ++k) Yr[13+i*9+j*3+k] = s7*hv[i]*hv[j]*hv[k];
}

// ---------------- CSR build ----------------
__global__ void k_hist(const int* __restrict__ recv, int* __restrict__ counts, int E)
{
    int e = blockIdx.x * blockDim.x + threadIdx.x;
    if (e < E) atomicAdd(&counts[recv[e]], 1);
}

__global__ void k_scan(const int* __restrict__ counts, int* __restrict__ offsets, int N)
{
    __shared__ int lds[1024];
    __shared__ int basev;
    if (threadIdx.x == 0) basev = 0;
    __syncthreads();
    for (int start = 0; start < N; start += 1024) {
        int i = start + (int)threadIdx.x;
        int v = (i < N) ? counts[i] : 0;
        lds[threadIdx.x] = v;
        __syncthreads();
        for (int off = 1; off < 1024; off <<= 1) {
            int add = (threadIdx.x >= (unsigned)off) ? lds[threadIdx.x - off] : 0;
            __syncthreads();
            lds[threadIdx.x] += add;
            __syncthreads();
        }
        if (i < N) offsets[i] = basev + lds[threadIdx.x] - v;  // exclusive
        __syncthreads();
        if (threadIdx.x == 1023) basev += lds[1023];
        __syncthreads();
    }
    if (threadIdx.x == 0) offsets[N] = basev;
}

__global__ void k_scatter(const int* __restrict__ recv,
                          const int* __restrict__ offsets,
                          int* __restrict__ cursor,
                          int* __restrict__ elist, int E)
{
    int e = blockIdx.x * blockDim.x + threadIdx.x;
    if (e >= E) return;
    int r = recv[e];
    int p = atomicAdd(&cursor[r], 1);
    elist[offsets[r] + p] = e;
}

__global__ void k_sort(const int* __restrict__ offsets, int* __restrict__ elist, int N)
{
    int n = blockIdx.x * blockDim.x + threadIdx.x;
    if (n >= N) return;
    int b = offsets[n], e2 = offsets[n+1];
    for (int i = b + 1; i < e2; ++i) {
        int v = elist[i];
        int j = i - 1;
        while (j >= b && elist[j] > v) { elist[j+1] = elist[j]; --j; }
        elist[j+1] = v;
    }
}

__global__ void k_embed(const int* __restrict__ species,
                        const float* __restrict__ embw,
                        float* __restrict__ h0, int NC)
{
    int i = blockIdx.x * blockDim.x + threadIdx.x;
    if (i >= NC) return;
    int n = i >> 6, c = i & 63;
    h0[i] = embw[species[n]*64 + c];
}

// ---------------- radial MLP (both layers, rank-split, 1 wave/block) -------
// block wid -> (layer l, edge-group g, rank-half). Lane = edge within group.
// Hidden state in registers; weights wave-uniform -> scalar-operand FMAs.
// Transpose to [E,256] layout in two 32-channel chunks through a [64][33]
// LDS tile: acc chunk fully dumped to LDS BEFORE each barrier (spill-free).
__global__ __launch_bounds__(64) void k_radial_mlp(
    const float* __restrict__ rb,       // [E,8]
    const float* __restrict__ rw1,      // [L,8,64]
    const float* __restrict__ rw2,      // [L,64,64]
    const float* __restrict__ rw3,      // [L,64,64]
    const float* __restrict__ rw4,      // [L,64,256]
    float* __restrict__ Rbuf,           // [nl,E,256]
    int lbase, int nl, int E, int ngroups)
{
    __shared__ float xch[64][33];       // 8.45 KB
    int lane = threadIdx.x;
    int wid  = blockIdx.x;
    int l    = wid / (ngroups * 2);
    int rem  = wid % (ngroups * 2);
    int g    = rem >> 1;
    int half = rem & 1;
    int layer = lbase + l;

    const float* w1 = rw1 + (size_t)layer * 8 * 64;
    const float* w2 = rw2 + (size_t)layer * 64 * 64;
    const float* w3 = rw3 + (size_t)layer * 64 * 64;
    const float* w4 = rw4 + (size_t)layer * 64 * 256;

    int base = g * 64;
    int e = base + lane;
    bool val = (e < E);

    float rbv[8];
    #pragma unroll
    for (int k = 0; k < 8; ++k) rbv[k] = val ? rb[(size_t)e*8 + k] : 0.0f;

    float ha[64], hb[64];
    // stage 1: ha = silu(rb @ w1)
    #pragma unroll
    for (int c = 0; c < 64; ++c) ha[c] = 0.0f;
    #pragma unroll
    for (int k = 0; k < 8; ++k) {
        float v = rbv[k];
        #pragma unroll
        for (int c = 0; c < 64; ++c) ha[c] = fmaf(v, w1[k*64 + c], ha[c]);
    }
    #pragma unroll
    for (int c = 0; c < 64; ++c) ha[c] = silu_f(ha[c]);

    // stage 2: hb = silu(ha @ w2)
    #pragma unroll
    for (int c = 0; c < 64; ++c) hb[c] = 0.0f;
    #pragma unroll
    for (int j = 0; j < 64; ++j) {
        float v = ha[j];
        #pragma unroll
        for (int c = 0; c < 64; ++c) hb[c] = fmaf(v, w2[j*64 + c], hb[c]);
    }
    #pragma unroll
    for (int c = 0; c < 64; ++c) hb[c] = silu_f(hb[c]);

    // stage 3: ha = silu(hb @ w3)
    #pragma unroll
    for (int c = 0; c < 64; ++c) ha[c] = 0.0f;
    #pragma unroll
    for (int j = 0; j < 64; ++j) {
        float v = hb[j];
        #pragma unroll
        for (int c = 0; c < 64; ++c) ha[c] = fmaf(v, w3[j*64 + c], ha[c]);
    }
    #pragma unroll
    for (int c = 0; c < 64; ++c) ha[c] = silu_f(ha[c]);

    // stage 4: my 2 ranks of R = ha @ w4[:, ri*64:+64]; transposed store.
    for (int rr = 0; rr < 2; ++rr) {
        int ri = half * 2 + rr;
        const float* w4r = w4 + ri * 64;
        float acc[64];
        #pragma unroll
        for (int c = 0; c < 64; ++c) acc[c] = 0.0f;
        #pragma unroll
        for (int j = 0; j < 64; ++j) {
            float v = ha[j];
            #pragma unroll
            for (int c = 0; c < 64; ++c)
                acc[c] = fmaf(v, w4r[j*256 + c], acc[c]);
        }
        float* outb = Rbuf + ((size_t)l * E) * 256 + (size_t)ri * 64;
        #pragma unroll
        for (int ch = 0; ch < 2; ++ch) {
            // dump my edge's 32-channel chunk (acc chunk dies here -> no spill)
            #pragma unroll
            for (int cc = 0; cc < 32; ++cc) xch[lane][cc] = acc[ch*32 + cc];
            __syncthreads();
            // read out: lanes 0-31 cover channels of edge et, lanes 32-63 edge et+1
            int cid = lane & 31;
            int eh  = lane >> 5;
            #pragma unroll
            for (int it = 0; it < 32; ++it) {
                int et = it*2 + eh;
                int e2 = base + et;
                if (e2 < E)
                    outb[(size_t)e2 * 256 + ch*32 + cid] = xch[et][cid];
            }
            __syncthreads();
        }
    }
}

// ---------------- node gather + contraction + mix + readout ----------------
__global__ __launch_bounds__(256) void k_node(
    const float* __restrict__ Rbuf,    // [E,256] this layer
    const float* __restrict__ h0,      // [N,64] input features
    const int*   __restrict__ senders, // [E]
    const float* __restrict__ Yb,      // [E,40]
    const int*   __restrict__ offsets, // [N+1]
    const int*   __restrict__ elist,   // [E]
    const float* __restrict__ mixw,    // [4,64,64] (this layer)
    const float* __restrict__ readw,   // [64]      (this layer)
    float* __restrict__ h0n,           // [N,64]
    const float* __restrict__ eprev,   // [N] or null
    float* __restrict__ eout,          // [N]
    int N)
{
    int gtid = blockIdx.x * blockDim.x + threadIdx.x;
    int wave = gtid >> 6;
    int lane = threadIdx.x & 63;
    int w    = threadIdx.x >> 6;
    __shared__ float Bl[4][4][64];
    bool active = (wave < N);
    int n = active ? wave : 0;

    float A[40];
    #pragma unroll
    for (int d = 0; d < 40; ++d) A[d] = 0.0f;

    if (active) {
        int beg = offsets[n], end = offsets[n+1];
        for (int i = beg; i < end; ++i) {
            int e = elist[i];
            int snd = senders[e];
            const float* Yr = Yb + (size_t)e*40;
            const float* Rr = Rbuf + (size_t)e*256;
            float hj = h0[(size_t)snd*64 + lane];
            float t0 = Rr[lane]       * hj;
            float t1 = Rr[64 + lane]  * hj;
            float t2 = Rr[128 + lane] * hj;
            float t3 = Rr[192 + lane] * hj;
            A[0] = fmaf(t0, Yr[0], A[0]);
            #pragma unroll
            for (int d = 0; d < 3; ++d)  A[1+d]  = fmaf(t1, Yr[1+d],  A[1+d]);
            #pragma unroll
            for (int d = 0; d < 9; ++d)  A[4+d]  = fmaf(t2, Yr[4+d],  A[4+d]);
            #pragma unroll
            for (int d = 0; d < 27; ++d) A[13+d] = fmaf(t3, Yr[13+d], A[13+d]);
        }
    }
    const float inv = 1.0f / 16.0f;  // AVG_NEIGH
    #pragma unroll
    for (int d = 0; d < 40; ++d) A[d] *= inv;

    float B0 = A[0];
    float B1 = 0.f, B2 = 0.f, B3 = 0.f;
    #pragma unroll
    for (int d = 0; d < 3; ++d)  B1 = fmaf(A[1+d],  A[1+d],  B1);
    #pragma unroll
    for (int d = 0; d < 9; ++d)  B2 = fmaf(A[4+d],  A[4+d],  B2);
    #pragma unroll
    for (int d = 0; d < 27; ++d) B3 = fmaf(A[13+d], A[13+d], B3);

    Bl[w][0][lane] = B0;
    Bl[w][1][lane] = B1;
    Bl[w][2][lane] = B2;
    Bl[w][3][lane] = B3;
    __syncthreads();

    if (active) {
        float acc = 0.0f;
        for (int ri = 0; ri < 4; ++ri) {
            #pragma unroll 8
            for (int j = 0; j < 64; ++j)
                acc = fmaf(Bl[w][ri][j], mixw[(ri*64 + j)*64 + lane], acc);
        }
        h0n[(size_t)n*64 + lane] = acc;

        float evl = acc * readw[lane];
        #pragma unroll
        for (int off = 1; off < 64; off <<= 1) evl += __shfl_xor(evl, off, 64);
        if (lane == 0) {
            float o = evl;
            if (eprev) o += eprev[n];
            eout[n] = o;
        }
    }
}

// ---------------------------------------------------------------------------
extern "C" void kernel_launch(void* const* d_in, const int* in_sizes, int n_in,
                              void* d_out, int out_size, void* d_ws, size_t ws_size,
                              hipStream_t stream)
{
    const int*   species   = (const int*)  d_in[0];
    const int*   senders   = (const int*)  d_in[1];
    const int*   receivers = (const int*)  d_in[2];
    const float* edge_vec  = (const float*)d_in[3];
    const float* embed_w   = (const float*)d_in[4];
    const float* rad_w1    = (const float*)d_in[5];
    const float* rad_w2    = (const float*)d_in[6];
    const float* rad_w3    = (const float*)d_in[7];
    const float* rad_w4    = (const float*)d_in[8];
    const float* mix_w     = (const float*)d_in[9];
    const float* read_w    = (const float*)d_in[10];

    int N = in_sizes[0];
    int E = in_sizes[1];
    float* out = (float*)d_out;

    char* ws = (char*)d_ws;
    size_t off = 0;
    auto alloc = [&](size_t bytes) -> char* {
        char* p = ws + off;
        off = (off + bytes + 255) & ~(size_t)255;
        return p;
    };
    float* rb    = (float*)alloc((size_t)E*8*sizeof(float));
    float* Yb    = (float*)alloc((size_t)E*40*sizeof(float));
    float* h0a   = (float*)alloc((size_t)N*64*sizeof(float));
    float* h0b   = (float*)alloc((size_t)N*64*sizeof(float));
    float* ener  = (float*)alloc((size_t)N*sizeof(float));
    int* counts  = (int*)alloc((size_t)N*sizeof(int));
    int* offsets = (int*)alloc((size_t)(N+1)*sizeof(int));
    int* cursor  = (int*)alloc((size_t)N*sizeof(int));
    int* elist   = (int*)alloc((size_t)E*sizeof(int));

    // R buffer: both layers if workspace allows, else one layer at a time
    size_t rone = (size_t)E*256*sizeof(float);
    int nl = (off + 2*rone <= ws_size) ? 2 : 1;
    float* Rbuf = (float*)alloc((size_t)nl*rone);

    int ngroups = (E + 63) / 64;

    hipMemsetAsync(counts, 0, (size_t)N*sizeof(int), stream);
    hipMemsetAsync(cursor, 0, (size_t)N*sizeof(int), stream);

    k_edge_basis<<<(E + 255)/256, 256, 0, stream>>>(edge_vec, rb, Yb, E);
    k_hist<<<(E + 255)/256, 256, 0, stream>>>(receivers, counts, E);
    k_scan<<<1, 1024, 0, stream>>>(counts, offsets, N);
    k_scatter<<<(E + 255)/256, 256, 0, stream>>>(receivers, offsets, cursor, elist, E);
    k_sort<<<(N + 255)/256, 256, 0, stream>>>(offsets, elist, N);
    k_embed<<<((size_t)N*64 + 255)/256, 256, 0, stream>>>(species, embed_w, h0a, N*64);

    if (nl == 2) {
        int blocks = 2 * ngroups * 2;   // layer x group x rank-half
        k_radial_mlp<<<blocks, 64, 0, stream>>>(
            rb, rad_w1, rad_w2, rad_w3, rad_w4, Rbuf, 0, 2, E, ngroups);
    }

    float* hcur = h0a;
    float* hnxt = h0b;
    for (int l = 0; l < 2; ++l) {
        float* Rl = Rbuf;
        if (nl == 2) {
            Rl = Rbuf + (size_t)l * E * 256;
        } else {
            int blocks = ngroups * 2;
            k_radial_mlp<<<blocks, 64, 0, stream>>>(
                rb, rad_w1, rad_w2, rad_w3, rad_w4, Rbuf, l, 1, E, ngroups);
        }
        k_node<<<((size_t)N*64 + 255)/256, 256, 0, stream>>>(
            Rl, hcur, senders, Yb, offsets, elist,
            mix_w + (size_t)l*4*64*64,
            read_w + (size_t)l*64,
            hnxt,
            (l == 0) ? nullptr : ener,
            (l == 0) ? ener : out,
            N);
        float* tmp = hcur; hcur = hnxt; hnxt = tmp;
    }
}

// Round 4
// 499.755 us; speedup vs baseline: 13.2374x; 2.5108x over previous
//
#include <hip/hip_runtime.h>
#include <math.h>

// ---------------------------------------------------------------------------
// TACE (MACE-style equivariant GNN) forward on MI355X.
// N=5000 nodes, E=80000 edges, C=64, 2 layers, ranks 0..3 (dims 1,3,9,27).
//
// R4: radial MLP restructured lane=CHANNEL. Weights live per-lane in VGPRs
// (vector loads, L1-resident, reused across the wave's 16 edges); activations
// are broadcast with v_readlane (VALU) -> 2 VALU instr per 64 lane-MACs.
// This removes the scalar-path (s_load/K$) bottleneck that capped R3 at
// ~5% issue efficiency. Both layers in one dispatch (10000 waves).
// ---------------------------------------------------------------------------

#define PI_F 3.14159265358979323846f

__device__ __forceinline__ float silu_f(float x) {
    return x / (1.0f + expf(-x));
}

__device__ __forceinline__ float bcast_lane(float v, int j) {
    return __builtin_bit_cast(float,
        __builtin_amdgcn_readlane(__builtin_bit_cast(int, v), j));
}

// ---------------- edge basis + angular ----------------
__global__ void k_edge_basis(const float* __restrict__ ev,
                             float* __restrict__ rb,
                             float* __restrict__ Yb, int E)
{
    int e = blockIdx.x * blockDim.x + threadIdx.x;
    if (e >= E) return;
    float vx = ev[3*e+0], vy = ev[3*e+1], vz = ev[3*e+2];
    float r2 = vx*vx + vy*vy + vz*vz + 1e-12f;
    float r  = sqrtf(r2);
    float x  = r * 0.2f;                   // r / CUTOFF
    float x2 = x*x;
    float x5 = x2*x2*x;
    // env = 1 - 21 x^5 + 35 x^6 - 15 x^7   (P=5)
    float env = 1.0f + x5*(-21.0f + x*(35.0f - 15.0f*x));
    if (x >= 1.0f) env = 0.0f;
    float pref = 0.632455532033675866f / r * env;   // sqrt(2/5)/r * env
    float pix  = PI_F * x;
    float* rbp = rb + (size_t)e*8;
    #pragma unroll
    for (int k = 0; k < 8; ++k) rbp[k] = pref * sinf((float)(k+1) * pix);

    float ir = 1.0f / r;
    float hv[3];
    hv[0] = vx*ir; hv[1] = vy*ir; hv[2] = vz*ir;
    float* Yr = Yb + (size_t)e*40;
    const float s3 = 1.73205080756887729f;
    const float s5 = 2.23606797749978969f;
    const float s7 = 2.64575131106459059f;
    Yr[0] = 1.0f;
    #pragma unroll
    for (int i = 0; i < 3; ++i) Yr[1+i] = s3*hv[i];
    #pragma unroll
    for (int i = 0; i < 3; ++i)
        #pragma unroll
        for (int j = 0; j < 3; ++j) Yr[4+i*3+j] = s5*hv[i]*hv[j];
    #pragma unroll
    for (int i = 0; i < 3; ++i)
        #pragma unroll
        for (int j = 0; j < 3; ++j)
            #pragma unroll
            for (int k = 0; k < 3; ++k) Yr[13+i*9+j*3+k] = s7*hv[i]*hv[j]*hv[k];
}

// ---------------- CSR build ----------------
__global__ void k_hist(const int* __restrict__ recv, int* __restrict__ counts, int E)
{
    int e = blockIdx.x * blockDim.x + threadIdx.x;
    if (e < E) atomicAdd(&counts[recv[e]], 1);
}

__global__ void k_scan(const int* __restrict__ counts, int* __restrict__ offsets, int N)
{
    __shared__ int lds[1024];
    __shared__ int basev;
    if (threadIdx.x == 0) basev = 0;
    __syncthreads();
    for (int start = 0; start < N; start += 1024) {
        int i = start + (int)threadIdx.x;
        int v = (i < N) ? counts[i] : 0;
        lds[threadIdx.x] = v;
        __syncthreads();
        for (int off = 1; off < 1024; off <<= 1) {
            int add = (threadIdx.x >= (unsigned)off) ? lds[threadIdx.x - off] : 0;
            __syncthreads();
            lds[threadIdx.x] += add;
            __syncthreads();
        }
        if (i < N) offsets[i] = basev + lds[threadIdx.x] - v;  // exclusive
        __syncthreads();
        if (threadIdx.x == 1023) basev += lds[1023];
        __syncthreads();
    }
    if (threadIdx.x == 0) offsets[N] = basev;
}

__global__ void k_scatter(const int* __restrict__ recv,
                          const int* __restrict__ offsets,
                          int* __restrict__ cursor,
                          int* __restrict__ elist, int E)
{
    int e = blockIdx.x * blockDim.x + threadIdx.x;
    if (e >= E) return;
    int r = recv[e];
    int p = atomicAdd(&cursor[r], 1);
    elist[offsets[r] + p] = e;
}

__global__ void k_sort(const int* __restrict__ offsets, int* __restrict__ elist, int N)
{
    int n = blockIdx.x * blockDim.x + threadIdx.x;
    if (n >= N) return;
    int b = offsets[n], e2 = offsets[n+1];
    for (int i = b + 1; i < e2; ++i) {
        int v = elist[i];
        int j = i - 1;
        while (j >= b && elist[j] > v) { elist[j+1] = elist[j]; --j; }
        elist[j+1] = v;
    }
}

__global__ void k_embed(const int* __restrict__ species,
                        const float* __restrict__ embw,
                        float* __restrict__ h0, int NC)
{
    int i = blockIdx.x * blockDim.x + threadIdx.x;
    if (i >= NC) return;
    int n = i >> 6, c = i & 63;
    h0[i] = embw[species[n]*64 + c];
}

// ---------------- radial MLP: lane=channel, readlane broadcast -------------
// wave -> (layer l, 16-edge chunk). Lane = output channel. Weights per-lane
// in VGPRs (wr[64], reloaded per stage); activations h[p] (p=edge in chunk)
// broadcast across lanes with v_readlane. No LDS, no barriers, no s_loads
// of weights.
#define MLP_P 16

__global__ __launch_bounds__(256) void k_radial_mlp(
    const float* __restrict__ rb,       // [E,8]
    const float* __restrict__ rw1,      // [L,8,64]
    const float* __restrict__ rw2,      // [L,64,64]
    const float* __restrict__ rw3,      // [L,64,64]
    const float* __restrict__ rw4,      // [L,64,256]
    float* __restrict__ Rbuf,           // [2,E,256]
    int E, int chunks_per_layer)
{
    int lane = threadIdx.x & 63;
    int wid  = blockIdx.x * 4 + (threadIdx.x >> 6);
    int total = 2 * chunks_per_layer;
    if (wid >= total) return;
    int l     = wid / chunks_per_layer;
    int chunk = wid % chunks_per_layer;
    int e0    = chunk * MLP_P;

    const float* w1 = rw1 + (size_t)l * 8 * 64;
    const float* w2 = rw2 + (size_t)l * 64 * 64;
    const float* w3 = rw3 + (size_t)l * 64 * 64;
    const float* w4 = rw4 + (size_t)l * 64 * 256;

    float h[MLP_P];
    float wr[64];

    // ---- stage 1: h = silu(rb @ w1), K=8 ----
    #pragma unroll
    for (int p = 0; p < MLP_P; ++p) {
        int e = e0 + p;
        float v = 0.0f;
        if (lane < 8 && e < E) v = rb[(size_t)e*8 + lane];
        h[p] = v;   // lanes 0-7 hold rb, rest 0
    }
    #pragma unroll
    for (int j = 0; j < 8; ++j) wr[j] = w1[j*64 + lane];
    #pragma unroll
    for (int p = 0; p < MLP_P; ++p) {
        float a0 = 0.f, a1 = 0.f;
        #pragma unroll
        for (int j = 0; j < 8; j += 2) {
            a0 = fmaf(bcast_lane(h[p], j),   wr[j],   a0);
            a1 = fmaf(bcast_lane(h[p], j+1), wr[j+1], a1);
        }
        h[p] = silu_f(a0 + a1);   // safe: h[p] only read for its own dot
    }

    // ---- stage 2: h = silu(h @ w2), K=64 ----
    #pragma unroll
    for (int j = 0; j < 64; ++j) wr[j] = w2[j*64 + lane];
    #pragma unroll
    for (int p = 0; p < MLP_P; ++p) {
        float a0 = 0.f, a1 = 0.f, a2 = 0.f, a3 = 0.f;
        #pragma unroll
        for (int j = 0; j < 64; j += 4) {
            a0 = fmaf(bcast_lane(h[p], j),   wr[j],   a0);
            a1 = fmaf(bcast_lane(h[p], j+1), wr[j+1], a1);
            a2 = fmaf(bcast_lane(h[p], j+2), wr[j+2], a2);
            a3 = fmaf(bcast_lane(h[p], j+3), wr[j+3], a3);
        }
        h[p] = silu_f((a0 + a1) + (a2 + a3));
    }

    // ---- stage 3: h = silu(h @ w3), K=64 ----
    #pragma unroll
    for (int j = 0; j < 64; ++j) wr[j] = w3[j*64 + lane];
    #pragma unroll
    for (int p = 0; p < MLP_P; ++p) {
        float a0 = 0.f, a1 = 0.f, a2 = 0.f, a3 = 0.f;
        #pragma unroll
        for (int j = 0; j < 64; j += 4) {
            a0 = fmaf(bcast_lane(h[p], j),   wr[j],   a0);
            a1 = fmaf(bcast_lane(h[p], j+1), wr[j+1], a1);
            a2 = fmaf(bcast_lane(h[p], j+2), wr[j+2], a2);
            a3 = fmaf(bcast_lane(h[p], j+3), wr[j+3], a3);
        }
        h[p] = silu_f((a0 + a1) + (a2 + a3));
    }

    // ---- stage 4: R[:, ri*64+lane] = h @ w4 slice, 4 rank slices ----
    float* outb = Rbuf + ((size_t)l * E + e0) * 256;
    #pragma unroll
    for (int ri = 0; ri < 4; ++ri) {
        #pragma unroll
        for (int j = 0; j < 64; ++j) wr[j] = w4[j*256 + ri*64 + lane];
        #pragma unroll
        for (int p = 0; p < MLP_P; ++p) {
            float a0 = 0.f, a1 = 0.f, a2 = 0.f, a3 = 0.f;
            #pragma unroll
            for (int j = 0; j < 64; j += 4) {
                a0 = fmaf(bcast_lane(h[p], j),   wr[j],   a0);
                a1 = fmaf(bcast_lane(h[p], j+1), wr[j+1], a1);
                a2 = fmaf(bcast_lane(h[p], j+2), wr[j+2], a2);
                a3 = fmaf(bcast_lane(h[p], j+3), wr[j+3], a3);
            }
            if (e0 + p < E)
                outb[(size_t)p * 256 + ri*64 + lane] = (a0 + a1) + (a2 + a3);
        }
    }
}

// ---------------- node gather + contraction + mix + readout ----------------
__global__ __launch_bounds__(256) void k_node(
    const float* __restrict__ Rbuf,    // [E,256] this layer
    const float* __restrict__ h0,      // [N,64] input features
    const int*   __restrict__ senders, // [E]
    const float* __restrict__ Yb,      // [E,40]
    const int*   __restrict__ offsets, // [N+1]
    const int*   __restrict__ elist,   // [E]
    const float* __restrict__ mixw,    // [4,64,64] (this layer)
    const float* __restrict__ readw,   // [64]      (this layer)
    float* __restrict__ h0n,           // [N,64]
    const float* __restrict__ eprev,   // [N] or null
    float* __restrict__ eout,          // [N]
    int N)
{
    int gtid = blockIdx.x * blockDim.x + threadIdx.x;
    int wave = gtid >> 6;
    int lane = threadIdx.x & 63;
    int w    = threadIdx.x >> 6;
    __shared__ float Bl[4][4][64];
    bool active = (wave < N);
    int n = active ? wave : 0;

    float A[40];
    #pragma unroll
    for (int d = 0; d < 40; ++d) A[d] = 0.0f;

    if (active) {
        int beg = offsets[n], end = offsets[n+1];
        for (int i = beg; i < end; ++i) {
            int e = elist[i];
            int snd = senders[e];
            const float* Yr = Yb + (size_t)e*40;
            const float* Rr = Rbuf + (size_t)e*256;
            float hj = h0[(size_t)snd*64 + lane];
            float t0 = Rr[lane]       * hj;
            float t1 = Rr[64 + lane]  * hj;
            float t2 = Rr[128 + lane] * hj;
            float t3 = Rr[192 + lane] * hj;
            A[0] = fmaf(t0, Yr[0], A[0]);
            #pragma unroll
            for (int d = 0; d < 3; ++d)  A[1+d]  = fmaf(t1, Yr[1+d],  A[1+d]);
            #pragma unroll
            for (int d = 0; d < 9; ++d)  A[4+d]  = fmaf(t2, Yr[4+d],  A[4+d]);
            #pragma unroll
            for (int d = 0; d < 27; ++d) A[13+d] = fmaf(t3, Yr[13+d], A[13+d]);
        }
    }
    const float inv = 1.0f / 16.0f;  // AVG_NEIGH
    #pragma unroll
    for (int d = 0; d < 40; ++d) A[d] *= inv;

    float B0 = A[0];
    float B1 = 0.f, B2 = 0.f, B3 = 0.f;
    #pragma unroll
    for (int d = 0; d < 3; ++d)  B1 = fmaf(A[1+d],  A[1+d],  B1);
    #pragma unroll
    for (int d = 0; d < 9; ++d)  B2 = fmaf(A[4+d],  A[4+d],  B2);
    #pragma unroll
    for (int d = 0; d < 27; ++d) B3 = fmaf(A[13+d], A[13+d], B3);

    Bl[w][0][lane] = B0;
    Bl[w][1][lane] = B1;
    Bl[w][2][lane] = B2;
    Bl[w][3][lane] = B3;
    __syncthreads();

    if (active) {
        float acc = 0.0f;
        for (int ri = 0; ri < 4; ++ri) {
            #pragma unroll 8
            for (int j = 0; j < 64; ++j)
                acc = fmaf(Bl[w][ri][j], mixw[(ri*64 + j)*64 + lane], acc);
        }
        h0n[(size_t)n*64 + lane] = acc;

        float evl = acc * readw[lane];
        #pragma unroll
        for (int off = 1; off < 64; off <<= 1) evl += __shfl_xor(evl, off, 64);
        if (lane == 0) {
            float o = evl;
            if (eprev) o += eprev[n];
            eout[n] = o;
        }
    }
}

// ---------------------------------------------------------------------------
extern "C" void kernel_launch(void* const* d_in, const int* in_sizes, int n_in,
                              void* d_out, int out_size, void* d_ws, size_t ws_size,
                              hipStream_t stream)
{
    const int*   species   = (const int*)  d_in[0];
    const int*   senders   = (const int*)  d_in[1];
    const int*   receivers = (const int*)  d_in[2];
    const float* edge_vec  = (const float*)d_in[3];
    const float* embed_w   = (const float*)d_in[4];
    const float* rad_w1    = (const float*)d_in[5];
    const float* rad_w2    = (const float*)d_in[6];
    const float* rad_w3    = (const float*)d_in[7];
    const float* rad_w4    = (const float*)d_in[8];
    const float* mix_w     = (const float*)d_in[9];
    const float* read_w    = (const float*)d_in[10];

    int N = in_sizes[0];
    int E = in_sizes[1];
    float* out = (float*)d_out;

    char* ws = (char*)d_ws;
    size_t off = 0;
    auto alloc = [&](size_t bytes) -> char* {
        char* p = ws + off;
        off = (off + bytes + 255) & ~(size_t)255;
        return p;
    };
    float* rb    = (float*)alloc((size_t)E*8*sizeof(float));
    float* Yb    = (float*)alloc((size_t)E*40*sizeof(float));
    float* h0a   = (float*)alloc((size_t)N*64*sizeof(float));
    float* h0b   = (float*)alloc((size_t)N*64*sizeof(float));
    float* ener  = (float*)alloc((size_t)N*sizeof(float));
    int* counts  = (int*)alloc((size_t)N*sizeof(int));
    int* offsets = (int*)alloc((size_t)(N+1)*sizeof(int));
    int* cursor  = (int*)alloc((size_t)N*sizeof(int));
    int* elist   = (int*)alloc((size_t)E*sizeof(int));
    float* Rbuf  = (float*)alloc((size_t)2*E*256*sizeof(float));

    hipMemsetAsync(counts, 0, (size_t)N*sizeof(int), stream);
    hipMemsetAsync(cursor, 0, (size_t)N*sizeof(int), stream);

    k_edge_basis<<<(E + 255)/256, 256, 0, stream>>>(edge_vec, rb, Yb, E);
    k_hist<<<(E + 255)/256, 256, 0, stream>>>(receivers, counts, E);
    k_scan<<<1, 1024, 0, stream>>>(counts, offsets, N);
    k_scatter<<<(E + 255)/256, 256, 0, stream>>>(receivers, offsets, cursor, elist, E);
    k_sort<<<(N + 255)/256, 256, 0, stream>>>(offsets, elist, N);
    k_embed<<<((size_t)N*64 + 255)/256, 256, 0, stream>>>(species, embed_w, h0a, N*64);

    int chunks = (E + MLP_P - 1) / MLP_P;
    int waves  = 2 * chunks;
    k_radial_mlp<<<(waves + 3)/4, 256, 0, stream>>>(
        rb, rad_w1, rad_w2, rad_w3, rad_w4, Rbuf, E, chunks);

    float* hcur = h0a;
    float* hnxt = h0b;
    for (int l = 0; l < 2; ++l) {
        float* Rl = Rbuf + (size_t)l * E * 256;
        k_node<<<((size_t)N*64 + 255)/256, 256, 0, stream>>>(
            Rl, hcur, senders, Yb, offsets, elist,
            mix_w + (size_t)l*4*64*64,
            read_w + (size_t)l*64,
            hnxt,
            (l == 0) ? nullptr : ener,
            (l == 0) ? ener : out,
            N);
        float* tmp = hcur; hcur = hnxt; hnxt = tmp;
    }
}

// Round 5
// 270.458 us; speedup vs baseline: 24.4603x; 1.8478x over previous
//
#include <hip/hip_runtime.h>
#include <math.h>

// ---------------------------------------------------------------------------
// TACE (MACE-style equivariant GNN) forward on MI355X.
// N=5000 nodes, E=80000 edges, C=64, 2 layers, ranks 0..3 (dims 1,3,9,27).
//
// R5: radial MLP on the MATRIX pipe. Per wave, a 16-edge tile runs
// D[out,edge] = W^T[out,k] @ H[k,edge] with mfma_f32_16x16x32_f16.
// Weights pre-packed into fragment-ordered f16 (k_prep_w). Inter-stage
// layout fix-up through a small wave-local LDS tile (no barriers).
// R output packed f16x2 -> [E,128] u32 (halves Rbuf traffic).
// ---------------------------------------------------------------------------

#define PI_F 3.14159265358979323846f

typedef _Float16 f16x8 __attribute__((ext_vector_type(8)));
typedef float f32x4 __attribute__((ext_vector_type(4)));

union FU { uint4 u; f16x8 h; };

__device__ __forceinline__ float silu_f(float x) {
    return x / (1.0f + expf(-x));
}

__device__ __forceinline__ uint pack2_f16(float a, float b) {
    unsigned short lo = __builtin_bit_cast(unsigned short, (_Float16)a);
    unsigned short hi = __builtin_bit_cast(unsigned short, (_Float16)b);
    return (uint)lo | ((uint)hi << 16);
}

__device__ __forceinline__ float unpk_f16(uint u, int hi) {
    unsigned short s = hi ? (unsigned short)(u >> 16) : (unsigned short)(u & 0xffff);
    return (float)__builtin_bit_cast(_Float16, s);
}

// ---------------- edge basis + angular ----------------
__global__ void k_edge_basis(const float* __restrict__ ev,
                             uint* __restrict__ rbh,     // [E,4] u32 (8 f16)
                             float* __restrict__ Yb, int E)
{
    int e = blockIdx.x * blockDim.x + threadIdx.x;
    if (e >= E) return;
    float vx = ev[3*e+0], vy = ev[3*e+1], vz = ev[3*e+2];
    float r2 = vx*vx + vy*vy + vz*vz + 1e-12f;
    float r  = sqrtf(r2);
    float x  = r * 0.2f;                   // r / CUTOFF
    float x2 = x*x;
    float x5 = x2*x2*x;
    float env = 1.0f + x5*(-21.0f + x*(35.0f - 15.0f*x));
    if (x >= 1.0f) env = 0.0f;
    float pref = 0.632455532033675866f / r * env;   // sqrt(2/5)/r * env
    float pix  = PI_F * x;
    float bas[8];
    #pragma unroll
    for (int k = 0; k < 8; ++k) bas[k] = pref * sinf((float)(k+1) * pix);
    uint* o = rbh + (size_t)e*4;
    #pragma unroll
    for (int k = 0; k < 4; ++k) o[k] = pack2_f16(bas[2*k], bas[2*k+1]);

    float ir = 1.0f / r;
    float hv[3];
    hv[0] = vx*ir; hv[1] = vy*ir; hv[2] = vz*ir;
    float* Yr = Yb + (size_t)e*40;
    const float s3 = 1.73205080756887729f;
    const float s5 = 2.23606797749978969f;
    const float s7 = 2.64575131106459059f;
    Yr[0] = 1.0f;
    #pragma unroll
    for (int i = 0; i < 3; ++i) Yr[1+i] = s3*hv[i];
    #pragma unroll
    for (int i = 0; i < 3; ++i)
        #pragma unroll
        for (int j = 0; j < 3; ++j) Yr[4+i*3+j] = s5*hv[i]*hv[j];
    #pragma unroll
    for (int i = 0; i < 3; ++i)
        #pragma unroll
        for (int j = 0; j < 3; ++j)
            #pragma unroll
            for (int k = 0; k < 3; ++k) Yr[13+i*9+j*3+k] = s7*hv[i]*hv[j]*hv[k];
}

// ---------------- CSR build ----------------
__global__ void k_hist(const int* __restrict__ recv, int* __restrict__ counts, int E)
{
    int e = blockIdx.x * blockDim.x + threadIdx.x;
    if (e < E) atomicAdd(&counts[recv[e]], 1);
}

__global__ void k_scan(const int* __restrict__ counts, int* __restrict__ offsets, int N)
{
    __shared__ int lds[1024];
    __shared__ int basev;
    if (threadIdx.x == 0) basev = 0;
    __syncthreads();
    for (int start = 0; start < N; start += 1024) {
        int i = start + (int)threadIdx.x;
        int v = (i < N) ? counts[i] : 0;
        lds[threadIdx.x] = v;
        __syncthreads();
        for (int off = 1; off < 1024; off <<= 1) {
            int add = (threadIdx.x >= (unsigned)off) ? lds[threadIdx.x - off] : 0;
            __syncthreads();
            lds[threadIdx.x] += add;
            __syncthreads();
        }
        if (i < N) offsets[i] = basev + lds[threadIdx.x] - v;  // exclusive
        __syncthreads();
        if (threadIdx.x == 1023) basev += lds[1023];
        __syncthreads();
    }
    if (threadIdx.x == 0) offsets[N] = basev;
}

__global__ void k_scatter(const int* __restrict__ recv,
                          const int* __restrict__ offsets,
                          int* __restrict__ cursor,
                          int* __restrict__ elist, int E)
{
    int e = blockIdx.x * blockDim.x + threadIdx.x;
    if (e >= E) return;
    int r = recv[e];
    int p = atomicAdd(&cursor[r], 1);
    elist[offsets[r] + p] = e;
}

__global__ void k_sort(const int* __restrict__ offsets, int* __restrict__ elist, int N)
{
    int n = blockIdx.x * blockDim.x + threadIdx.x;
    if (n >= N) return;
    int b = offsets[n], e2 = offsets[n+1];
    for (int i = b + 1; i < e2; ++i) {
        int v = elist[i];
        int j = i - 1;
        while (j >= b && elist[j] > v) { elist[j+1] = elist[j]; --j; }
        elist[j+1] = v;
    }
}

__global__ void k_embed(const int* __restrict__ species,
                        const float* __restrict__ embw,
                        float* __restrict__ h0, int NC)
{
    int i = blockIdx.x * blockDim.x + threadIdx.x;
    if (i >= NC) return;
    int n = i >> 6, c = i & 63;
    h0[i] = embw[species[n]*64 + c];
}

// ---------------- weight prep: fragment-ordered f16 ----------------
// A-frag for W^T tile [16 out x 32 k]: lane holds out = 16*ot + (lane&15),
// k = 32*kt + 8*(lane>>4) + {0..7}, as 4 u32 (f16x2 pairs, lo = even k).
// Wf1: [2][4][64][4]        (2048 u32, k>=8 zero)
// Wf2: [2][4][2][64][4]     (4096)   [l][ot][kt][lane][reg]
// Wf3: same as Wf2          (4096)
// Wf4: [2][16][2][64][4]    (16384)  [l][ot][kt][lane][reg]
__global__ void k_prep_w(const float* __restrict__ rw1,   // [2,8,64]
                         const float* __restrict__ rw2,   // [2,64,64]
                         const float* __restrict__ rw3,   // [2,64,64]
                         const float* __restrict__ rw4,   // [2,64,256]
                         uint* __restrict__ Wf1, uint* __restrict__ Wf2,
                         uint* __restrict__ Wf3, uint* __restrict__ Wf4)
{
    int tid = blockIdx.x * blockDim.x + threadIdx.x;
    if (tid < 2048) {
        int reg = tid & 3, lane = (tid >> 2) & 63, ot = (tid >> 8) & 3, l = tid >> 10;
        int out = 16*ot + (lane & 15);
        int k   = 8*(lane >> 4) + 2*reg;
        float lo = (k   < 8) ? rw1[l*512 + k*64 + out]     : 0.0f;
        float hi = (k+1 < 8) ? rw1[l*512 + (k+1)*64 + out] : 0.0f;
        Wf1[tid] = pack2_f16(lo, hi);
        return;
    }
    int t = tid - 2048;
    if (t < 4096) {
        int reg = t & 3, lane = (t >> 2) & 63, kt = (t >> 8) & 1, ot = (t >> 9) & 3, l = t >> 11;
        int out = 16*ot + (lane & 15);
        int k   = 32*kt + 8*(lane >> 4) + 2*reg;
        Wf2[t] = pack2_f16(rw2[l*4096 + k*64 + out], rw2[l*4096 + (k+1)*64 + out]);
        return;
    }
    t -= 4096;
    if (t < 4096) {
        int reg = t & 3, lane = (t >> 2) & 63, kt = (t >> 8) & 1, ot = (t >> 9) & 3, l = t >> 11;
        int out = 16*ot + (lane & 15);
        int k   = 32*kt + 8*(lane >> 4) + 2*reg;
        Wf3[t] = pack2_f16(rw3[l*4096 + k*64 + out], rw3[l*4096 + (k+1)*64 + out]);
        return;
    }
    t -= 4096;
    if (t < 16384) {
        int reg = t & 3, lane = (t >> 2) & 63, kt = (t >> 8) & 1, ot = (t >> 9) & 15, l = t >> 13;
        int out = 16*ot + (lane & 15);   // column in [64,256]
        int k   = 32*kt + 8*(lane >> 4) + 2*reg;
        Wf4[t] = pack2_f16(rw4[l*16384 + k*256 + out], rw4[l*16384 + (k+1)*256 + out]);
    }
}

// ---------------- radial MLP via MFMA ----------------
// One wave per (layer, 16-edge tile). H staged in wave-local LDS [16][36] u32
// (f16x2, row=edge, col=channel-pair; stride 144B keeps b128 alignment).
__global__ __launch_bounds__(256) void k_mlp_mfma(
    const uint* __restrict__ rbh,    // [E,4] u32 (8 f16)
    const uint* __restrict__ Wf1, const uint* __restrict__ Wf2,
    const uint* __restrict__ Wf3, const uint* __restrict__ Wf4,
    uint* __restrict__ Rpk,          // [2,E,128] u32 (f16x2)
    int E, int tiles)
{
    __shared__ __align__(16) uint Hl[4][16][36];
    int lane = threadIdx.x & 63;
    int w    = threadIdx.x >> 6;
    int wid  = blockIdx.x * 4 + w;
    if (wid >= 2 * tiles) return;
    int l    = wid / tiles;
    int tile = wid % tiles;
    int e0   = tile * 16;

    uint (*H)[36] = Hl[w];
    int er = lane & 15;      // edge-in-tile (B col / D col)
    int kb = lane >> 4;      // k-group / row-group

    f32x4 zero4 = {0.f, 0.f, 0.f, 0.f};

    // ---- stage 1: D = W1^T @ rb ----
    FU b;
    if (kb == 0) {
        int e = e0 + er;
        if (e < E) b.u = *(const uint4*)(rbh + (size_t)e*4);
        else       b.u = make_uint4(0,0,0,0);
    } else {
        b.u = make_uint4(0,0,0,0);
    }
    f32x4 d[4];
    #pragma unroll
    for (int ot = 0; ot < 4; ++ot) {
        FU a;
        a.u = *(const uint4*)(Wf1 + ((size_t)(l*4 + ot)*64 + lane)*4);
        d[ot] = __builtin_amdgcn_mfma_f32_16x16x32_f16(a.h, b.h, zero4, 0, 0, 0);
    }
    // silu + pack + stage to LDS
    #pragma unroll
    for (int ot = 0; ot < 4; ++ot) {
        uint p0 = pack2_f16(silu_f(d[ot][0]), silu_f(d[ot][1]));
        uint p1 = pack2_f16(silu_f(d[ot][2]), silu_f(d[ot][3]));
        uint* dst = &H[er][8*ot + 2*kb];
        dst[0] = p0; dst[1] = p1;
    }

    // ---- stages 2,3: D = W^T @ H ----
    const uint* Wfs[2] = { Wf2, Wf3 };
    #pragma unroll
    for (int s = 0; s < 2; ++s) {
        FU hb0, hb1;
        hb0.u = *(const uint4*)&H[er][4*kb];
        hb1.u = *(const uint4*)&H[er][16 + 4*kb];
        #pragma unroll
        for (int ot = 0; ot < 4; ++ot) {
            FU a;
            a.u = *(const uint4*)(Wfs[s] + ((size_t)((l*4 + ot)*2 + 0)*64 + lane)*4);
            d[ot] = __builtin_amdgcn_mfma_f32_16x16x32_f16(a.h, hb0.h, zero4, 0, 0, 0);
            a.u = *(const uint4*)(Wfs[s] + ((size_t)((l*4 + ot)*2 + 1)*64 + lane)*4);
            d[ot] = __builtin_amdgcn_mfma_f32_16x16x32_f16(a.h, hb1.h, d[ot], 0, 0, 0);
        }
        #pragma unroll
        for (int ot = 0; ot < 4; ++ot) {
            uint p0 = pack2_f16(silu_f(d[ot][0]), silu_f(d[ot][1]));
            uint p1 = pack2_f16(silu_f(d[ot][2]), silu_f(d[ot][3]));
            uint* dst = &H[er][8*ot + 2*kb];
            dst[0] = p0; dst[1] = p1;
        }
    }

    // ---- stage 4: R = W4^T @ H, 4 ranks; pack f16x2; store via LDS ----
    FU hb0, hb1;
    hb0.u = *(const uint4*)&H[er][4*kb];
    hb1.u = *(const uint4*)&H[er][16 + 4*kb];
    #pragma unroll
    for (int ri = 0; ri < 4; ++ri) {
        #pragma unroll
        for (int otl = 0; otl < 4; ++otl) {
            int ot = ri*4 + otl;
            FU a;
            f32x4 d2;
            a.u = *(const uint4*)(Wf4 + ((size_t)((l*16 + ot)*2 + 0)*64 + lane)*4);
            d2 = __builtin_amdgcn_mfma_f32_16x16x32_f16(a.h, hb0.h, zero4, 0, 0, 0);
            a.u = *(const uint4*)(Wf4 + ((size_t)((l*16 + ot)*2 + 1)*64 + lane)*4);
            d2 = __builtin_amdgcn_mfma_f32_16x16x32_f16(a.h, hb1.h, d2, 0, 0, 0);
            uint p0 = pack2_f16(d2[0], d2[1]);
            uint p1 = pack2_f16(d2[2], d2[3]);
            uint* dst = &H[er][8*otl + 2*kb];   // reuse H as out-stage buffer
            dst[0] = p0; dst[1] = p1;
        }
        // flush rank tile [16 edges][32 u32] -> Rpk rows (128B contiguous/row)
        #pragma unroll
        for (int it = 0; it < 2; ++it) {
            int row  = it*8 + (lane >> 3);
            int col4 = (lane & 7) * 4;
            int eg   = e0 + row;
            if (eg < E) {
                *(uint4*)(Rpk + ((size_t)l*E + eg)*128 + ri*32 + col4) =
                    *(const uint4*)&H[row][col4];
            }
        }
    }
}

// ---------------- node gather + contraction + mix + readout ----------------
__global__ __launch_bounds__(256) void k_node(
    const uint*  __restrict__ Rpk,     // [E,128] u32 this layer (f16x2)
    const float* __restrict__ h0,      // [N,64] input features
    const int*   __restrict__ senders, // [E]
    const float* __restrict__ Yb,      // [E,40]
    const int*   __restrict__ offsets, // [N+1]
    const int*   __restrict__ elist,   // [E]
    const float* __restrict__ mixw,    // [4,64,64] (this layer)
    const float* __restrict__ readw,   // [64]      (this layer)
    float* __restrict__ h0n,           // [N,64]
    const float* __restrict__ eprev,   // [N] or null
    float* __restrict__ eout,          // [N]
    int N)
{
    int gtid = blockIdx.x * blockDim.x + threadIdx.x;
    int wave = gtid >> 6;
    int lane = threadIdx.x & 63;
    int w    = threadIdx.x >> 6;
    __shared__ float Bl[4][4][64];
    bool active = (wave < N);
    int n = active ? wave : 0;
    int half = lane & 1;
    int cpair = lane >> 1;

    float A[40];
    #pragma unroll
    for (int d = 0; d < 40; ++d) A[d] = 0.0f;

    if (active) {
        int beg = offsets[n], end = offsets[n+1];
        for (int i = beg; i < end; ++i) {
            int e = elist[i];
            int snd = senders[e];
            const float* Yr = Yb + (size_t)e*40;
            const uint*  Rr = Rpk + (size_t)e*128;
            float hj = h0[(size_t)snd*64 + lane];
            float t0 = unpk_f16(Rr[cpair],      half) * hj;
            float t1 = unpk_f16(Rr[32 + cpair], half) * hj;
            float t2 = unpk_f16(Rr[64 + cpair], half) * hj;
            float t3 = unpk_f16(Rr[96 + cpair], half) * hj;
            A[0] = fmaf(t0, Yr[0], A[0]);
            #pragma unroll
            for (int d = 0; d < 3; ++d)  A[1+d]  = fmaf(t1, Yr[1+d],  A[1+d]);
            #pragma unroll
            for (int d = 0; d < 9; ++d)  A[4+d]  = fmaf(t2, Yr[4+d],  A[4+d]);
            #pragma unroll
            for (int d = 0; d < 27; ++d) A[13+d] = fmaf(t3, Yr[13+d], A[13+d]);
        }
    }
    const float inv = 1.0f / 16.0f;  // AVG_NEIGH
    #pragma unroll
    for (int d = 0; d < 40; ++d) A[d] *= inv;

    float B0 = A[0];
    float B1 = 0.f, B2 = 0.f, B3 = 0.f;
    #pragma unroll
    for (int d = 0; d < 3; ++d)  B1 = fmaf(A[1+d],  A[1+d],  B1);
    #pragma unroll
    for (int d = 0; d < 9; ++d)  B2 = fmaf(A[4+d],  A[4+d],  B2);
    #pragma unroll
    for (int d = 0; d < 27; ++d) B3 = fmaf(A[13+d], A[13+d], B3);

    Bl[w][0][lane] = B0;
    Bl[w][1][lane] = B1;
    Bl[w][2][lane] = B2;
    Bl[w][3][lane] = B3;
    __syncthreads();

    if (active) {
        float acc = 0.0f;
        for (int ri = 0; ri < 4; ++ri) {
            #pragma unroll 8
            for (int j = 0; j < 64; ++j)
                acc = fmaf(Bl[w][ri][j], mixw[(ri*64 + j)*64 + lane], acc);
        }
        h0n[(size_t)n*64 + lane] = acc;

        float evl = acc * readw[lane];
        #pragma unroll
        for (int off = 1; off < 64; off <<= 1) evl += __shfl_xor(evl, off, 64);
        if (lane == 0) {
            float o = evl;
            if (eprev) o += eprev[n];
            eout[n] = o;
        }
    }
}

// ---------------------------------------------------------------------------
extern "C" void kernel_launch(void* const* d_in, const int* in_sizes, int n_in,
                              void* d_out, int out_size, void* d_ws, size_t ws_size,
                              hipStream_t stream)
{
    const int*   species   = (const int*)  d_in[0];
    const int*   senders   = (const int*)  d_in[1];
    const int*   receivers = (const int*)  d_in[2];
    const float* edge_vec  = (const float*)d_in[3];
    const float* embed_w   = (const float*)d_in[4];
    const float* rad_w1    = (const float*)d_in[5];
    const float* rad_w2    = (const float*)d_in[6];
    const float* rad_w3    = (const float*)d_in[7];
    const float* rad_w4    = (const float*)d_in[8];
    const float* mix_w     = (const float*)d_in[9];
    const float* read_w    = (const float*)d_in[10];

    int N = in_sizes[0];
    int E = in_sizes[1];
    float* out = (float*)d_out;

    char* ws = (char*)d_ws;
    size_t off = 0;
    auto alloc = [&](size_t bytes) -> char* {
        char* p = ws + off;
        off = (off + bytes + 255) & ~(size_t)255;
        return p;
    };
    uint*  rbh   = (uint*) alloc((size_t)E*4*sizeof(uint));
    float* Yb    = (float*)alloc((size_t)E*40*sizeof(float));
    float* h0a   = (float*)alloc((size_t)N*64*sizeof(float));
    float* h0b   = (float*)alloc((size_t)N*64*sizeof(float));
    float* ener  = (float*)alloc((size_t)N*sizeof(float));
    int* counts  = (int*)alloc((size_t)N*sizeof(int));
    int* offsets = (int*)alloc((size_t)(N+1)*sizeof(int));
    int* cursor  = (int*)alloc((size_t)N*sizeof(int));
    int* elist   = (int*)alloc((size_t)E*sizeof(int));
    uint* Wf1    = (uint*)alloc(2048*sizeof(uint));
    uint* Wf2    = (uint*)alloc(4096*sizeof(uint));
    uint* Wf3    = (uint*)alloc(4096*sizeof(uint));
    uint* Wf4    = (uint*)alloc(16384*sizeof(uint));
    uint* Rpk    = (uint*)alloc((size_t)2*E*128*sizeof(uint));

    hipMemsetAsync(counts, 0, (size_t)N*sizeof(int), stream);
    hipMemsetAsync(cursor, 0, (size_t)N*sizeof(int), stream);

    k_edge_basis<<<(E + 255)/256, 256, 0, stream>>>(edge_vec, rbh, Yb, E);
    k_prep_w<<<(26624 + 255)/256, 256, 0, stream>>>(
        rad_w1, rad_w2, rad_w3, rad_w4, Wf1, Wf2, Wf3, Wf4);
    k_hist<<<(E + 255)/256, 256, 0, stream>>>(receivers, counts, E);
    k_scan<<<1, 1024, 0, stream>>>(counts, offsets, N);
    k_scatter<<<(E + 255)/256, 256, 0, stream>>>(receivers, offsets, cursor, elist, E);
    k_sort<<<(N + 255)/256, 256, 0, stream>>>(offsets, elist, N);
    k_embed<<<((size_t)N*64 + 255)/256, 256, 0, stream>>>(species, embed_w, h0a, N*64);

    int tiles = (E + 15) / 16;
    int waves = 2 * tiles;
    k_mlp_mfma<<<(waves + 3)/4, 256, 0, stream>>>(
        rbh, Wf1, Wf2, Wf3, Wf4, Rpk, E, tiles);

    float* hcur = h0a;
    float* hnxt = h0b;
    for (int l = 0; l < 2; ++l) {
        uint* Rl = Rpk + (size_t)l * E * 128;
        k_node<<<((size_t)N*64 + 255)/256, 256, 0, stream>>>(
            Rl, hcur, senders, Yb, offsets, elist,
            mix_w + (size_t)l*4*64*64,
            read_w + (size_t)l*64,
            hnxt,
            (l == 0) ? nullptr : ener,
            (l == 0) ? ener : out,
            N);
        float* tmp = hcur; hcur = hnxt; hnxt = tmp;
    }
}

// Round 6
// 208.832 us; speedup vs baseline: 31.6784x; 1.2951x over previous
//
#include <hip/hip_runtime.h>
#include <math.h>

// ---------------------------------------------------------------------------
// TACE (MACE-style equivariant GNN) forward on MI355X.
// N=5000 nodes, E=80000 edges, C=64, 2 layers, ranks 0..3 (dims 1,3,9,27).
//
// R6: replace serial per-thread insertion sort (71us, 0.6% occupancy) with
// wave-parallel rank sort (one wave per node, shfl-compare ranking); replace
// barrier-heavy scan with wave-shuffle scan. MLP stays on the matrix pipe
// (R5 structure: mfma_f32_16x16x32_f16, fragment-packed weights, f16x2 R).
// ---------------------------------------------------------------------------

#define PI_F 3.14159265358979323846f

typedef _Float16 f16x8 __attribute__((ext_vector_type(8)));
typedef float f32x4 __attribute__((ext_vector_type(4)));

union FU { uint4 u; f16x8 h; };

__device__ __forceinline__ float silu_f(float x) {
    return x / (1.0f + expf(-x));
}

__device__ __forceinline__ uint pack2_f16(float a, float b) {
    unsigned short lo = __builtin_bit_cast(unsigned short, (_Float16)a);
    unsigned short hi = __builtin_bit_cast(unsigned short, (_Float16)b);
    return (uint)lo | ((uint)hi << 16);
}

__device__ __forceinline__ float unpk_f16(uint u, int hi) {
    unsigned short s = hi ? (unsigned short)(u >> 16) : (unsigned short)(u & 0xffff);
    return (float)__builtin_bit_cast(_Float16, s);
}

// ---------------- edge basis + angular ----------------
__global__ void k_edge_basis(const float* __restrict__ ev,
                             uint* __restrict__ rbh,     // [E,4] u32 (8 f16)
                             float* __restrict__ Yb, int E)
{
    int e = blockIdx.x * blockDim.x + threadIdx.x;
    if (e >= E) return;
    float vx = ev[3*e+0], vy = ev[3*e+1], vz = ev[3*e+2];
    float r2 = vx*vx + vy*vy + vz*vz + 1e-12f;
    float r  = sqrtf(r2);
    float x  = r * 0.2f;                   // r / CUTOFF
    float x2 = x*x;
    float x5 = x2*x2*x;
    float env = 1.0f + x5*(-21.0f + x*(35.0f - 15.0f*x));
    if (x >= 1.0f) env = 0.0f;
    float pref = 0.632455532033675866f / r * env;   // sqrt(2/5)/r * env
    float pix  = PI_F * x;
    float bas[8];
    #pragma unroll
    for (int k = 0; k < 8; ++k) bas[k] = pref * sinf((float)(k+1) * pix);
    uint* o = rbh + (size_t)e*4;
    #pragma unroll
    for (int k = 0; k < 4; ++k) o[k] = pack2_f16(bas[2*k], bas[2*k+1]);

    float ir = 1.0f / r;
    float hv[3];
    hv[0] = vx*ir; hv[1] = vy*ir; hv[2] = vz*ir;
    float* Yr = Yb + (size_t)e*40;
    const float s3 = 1.73205080756887729f;
    const float s5 = 2.23606797749978969f;
    const float s7 = 2.64575131106459059f;
    Yr[0] = 1.0f;
    #pragma unroll
    for (int i = 0; i < 3; ++i) Yr[1+i] = s3*hv[i];
    #pragma unroll
    for (int i = 0; i < 3; ++i)
        #pragma unroll
        for (int j = 0; j < 3; ++j) Yr[4+i*3+j] = s5*hv[i]*hv[j];
    #pragma unroll
    for (int i = 0; i < 3; ++i)
        #pragma unroll
        for (int j = 0; j < 3; ++j)
            #pragma unroll
            for (int k = 0; k < 3; ++k) Yr[13+i*9+j*3+k] = s7*hv[i]*hv[j]*hv[k];
}

// ---------------- CSR build ----------------
__global__ void k_hist(const int* __restrict__ recv, int* __restrict__ counts, int E)
{
    int e = blockIdx.x * blockDim.x + threadIdx.x;
    if (e < E) atomicAdd(&counts[recv[e]], 1);
}

// 1024-thread single-block exclusive scan, wave-shuffle based (few barriers)
__global__ void k_scan(const int* __restrict__ counts, int* __restrict__ offsets, int N)
{
    __shared__ int wsum[16];
    __shared__ int basev;
    int lane = threadIdx.x & 63;
    int w    = threadIdx.x >> 6;
    if (threadIdx.x == 0) basev = 0;
    __syncthreads();
    for (int start = 0; start < N; start += 1024) {
        int i = start + (int)threadIdx.x;
        int v = (i < N) ? counts[i] : 0;
        // inclusive wave scan
        int s = v;
        #pragma unroll
        for (int off = 1; off < 64; off <<= 1) {
            int t = __shfl_up(s, off, 64);
            if (lane >= off) s += t;
        }
        if (lane == 63) wsum[w] = s;
        __syncthreads();
        int wbase = 0;
        {
            int ws = (lane < 16) ? wsum[lane] : 0;
            #pragma unroll
            for (int off = 1; off < 16; off <<= 1) {
                int t = __shfl_up(ws, off, 64);
                if (lane >= off) ws += t;
            }
            // broadcast exclusive base for wave w
            int excl = __shfl(ws, w - 1, 64);
            wbase = (w == 0) ? 0 : excl;
        }
        if (i < N) offsets[i] = basev + wbase + s - v;   // exclusive
        __syncthreads();
        if (threadIdx.x == 1023) basev += wbase + s;
        __syncthreads();
    }
    if (threadIdx.x == 0) offsets[N] = basev;
}

__global__ void k_scatter(const int* __restrict__ recv,
                          const int* __restrict__ offsets,
                          int* __restrict__ cursor,
                          int* __restrict__ elist, int E)
{
    int e = blockIdx.x * blockDim.x + threadIdx.x;
    if (e >= E) return;
    int r = recv[e];
    int p = atomicAdd(&cursor[r], 1);
    elist[offsets[r] + p] = e;
}

// wave-parallel rank sort: one wave per node (deterministic ascending order)
__global__ __launch_bounds__(256) void k_sort_wave(
    const int* __restrict__ offsets, int* __restrict__ elist, int N)
{
    int lane = threadIdx.x & 63;
    int node = (blockIdx.x * blockDim.x + threadIdx.x) >> 6;
    if (node >= N) return;
    int beg = offsets[node], end = offsets[node+1];
    int d = end - beg;
    if (d <= 1) return;
    if (d <= 64) {
        int v = (lane < d) ? elist[beg + lane] : 0x7fffffff;
        int rank = 0;
        #pragma unroll 8
        for (int j = 0; j < 64; ++j) {
            int vj = __shfl(v, j, 64);
            rank += (vj < v) ? 1 : 0;
        }
        if (lane < d) elist[beg + rank] = v;
    } else {
        if (lane == 0) {
            for (int i = beg + 1; i < end; ++i) {
                int v = elist[i];
                int j = i - 1;
                while (j >= beg && elist[j] > v) { elist[j+1] = elist[j]; --j; }
                elist[j+1] = v;
            }
        }
    }
}

__global__ void k_embed(const int* __restrict__ species,
                        const float* __restrict__ embw,
                        float* __restrict__ h0, int NC)
{
    int i = blockIdx.x * blockDim.x + threadIdx.x;
    if (i >= NC) return;
    int n = i >> 6, c = i & 63;
    h0[i] = embw[species[n]*64 + c];
}

// ---------------- weight prep: fragment-ordered f16 ----------------
// A-frag for W^T tile [16 out x 32 k]: lane holds out = 16*ot + (lane&15),
// k = 32*kt + 8*(lane>>4) + {0..7}, as 4 u32 (f16x2 pairs, lo = even k).
__global__ void k_prep_w(const float* __restrict__ rw1,   // [2,8,64]
                         const float* __restrict__ rw2,   // [2,64,64]
                         const float* __restrict__ rw3,   // [2,64,64]
                         const float* __restrict__ rw4,   // [2,64,256]
                         uint* __restrict__ Wf1, uint* __restrict__ Wf2,
                         uint* __restrict__ Wf3, uint* __restrict__ Wf4)
{
    int tid = blockIdx.x * blockDim.x + threadIdx.x;
    if (tid < 2048) {
        int reg = tid & 3, lane = (tid >> 2) & 63, ot = (tid >> 8) & 3, l = tid >> 10;
        int out = 16*ot + (lane & 15);
        int k   = 8*(lane >> 4) + 2*reg;
        float lo = (k   < 8) ? rw1[l*512 + k*64 + out]     : 0.0f;
        float hi = (k+1 < 8) ? rw1[l*512 + (k+1)*64 + out] : 0.0f;
        Wf1[tid] = pack2_f16(lo, hi);
        return;
    }
    int t = tid - 2048;
    if (t < 4096) {
        int reg = t & 3, lane = (t >> 2) & 63, kt = (t >> 8) & 1, ot = (t >> 9) & 3, l = t >> 11;
        int out = 16*ot + (lane & 15);
        int k   = 32*kt + 8*(lane >> 4) + 2*reg;
        Wf2[t] = pack2_f16(rw2[l*4096 + k*64 + out], rw2[l*4096 + (k+1)*64 + out]);
        return;
    }
    t -= 4096;
    if (t < 4096) {
        int reg = t & 3, lane = (t >> 2) & 63, kt = (t >> 8) & 1, ot = (t >> 9) & 3, l = t >> 11;
        int out = 16*ot + (lane & 15);
        int k   = 32*kt + 8*(lane >> 4) + 2*reg;
        Wf3[t] = pack2_f16(rw3[l*4096 + k*64 + out], rw3[l*4096 + (k+1)*64 + out]);
        return;
    }
    t -= 4096;
    if (t < 16384) {
        int reg = t & 3, lane = (t >> 2) & 63, kt = (t >> 8) & 1, ot = (t >> 9) & 15, l = t >> 13;
        int out = 16*ot + (lane & 15);   // column in [64,256]
        int k   = 32*kt + 8*(lane >> 4) + 2*reg;
        Wf4[t] = pack2_f16(rw4[l*16384 + k*256 + out], rw4[l*16384 + (k+1)*256 + out]);
    }
}

// ---------------- radial MLP via MFMA ----------------
__global__ __launch_bounds__(256) void k_mlp_mfma(
    const uint* __restrict__ rbh,    // [E,4] u32 (8 f16)
    const uint* __restrict__ Wf1, const uint* __restrict__ Wf2,
    const uint* __restrict__ Wf3, const uint* __restrict__ Wf4,
    uint* __restrict__ Rpk,          // [2,E,128] u32 (f16x2)
    int E, int tiles)
{
    __shared__ __align__(16) uint Hl[4][16][36];
    int lane = threadIdx.x & 63;
    int w    = threadIdx.x >> 6;
    int wid  = blockIdx.x * 4 + w;
    if (wid >= 2 * tiles) return;
    int l    = wid / tiles;
    int tile = wid % tiles;
    int e0   = tile * 16;

    uint (*H)[36] = Hl[w];
    int er = lane & 15;      // edge-in-tile (B col / D col)
    int kb = lane >> 4;      // k-group / row-group

    f32x4 zero4 = {0.f, 0.f, 0.f, 0.f};

    // ---- stage 1: D = W1^T @ rb ----
    FU b;
    if (kb == 0) {
        int e = e0 + er;
        if (e < E) b.u = *(const uint4*)(rbh + (size_t)e*4);
        else       b.u = make_uint4(0,0,0,0);
    } else {
        b.u = make_uint4(0,0,0,0);
    }
    f32x4 d[4];
    #pragma unroll
    for (int ot = 0; ot < 4; ++ot) {
        FU a;
        a.u = *(const uint4*)(Wf1 + ((size_t)(l*4 + ot)*64 + lane)*4);
        d[ot] = __builtin_amdgcn_mfma_f32_16x16x32_f16(a.h, b.h, zero4, 0, 0, 0);
    }
    #pragma unroll
    for (int ot = 0; ot < 4; ++ot) {
        uint p0 = pack2_f16(silu_f(d[ot][0]), silu_f(d[ot][1]));
        uint p1 = pack2_f16(silu_f(d[ot][2]), silu_f(d[ot][3]));
        uint* dst = &H[er][8*ot + 2*kb];
        dst[0] = p0; dst[1] = p1;
    }

    // ---- stages 2,3: D = W^T @ H ----
    const uint* Wfs[2] = { Wf2, Wf3 };
    #pragma unroll
    for (int s = 0; s < 2; ++s) {
        FU hb0, hb1;
        hb0.u = *(const uint4*)&H[er][4*kb];
        hb1.u = *(const uint4*)&H[er][16 + 4*kb];
        #pragma unroll
        for (int ot = 0; ot < 4; ++ot) {
            FU a;
            a.u = *(const uint4*)(Wfs[s] + ((size_t)((l*4 + ot)*2 + 0)*64 + lane)*4);
            d[ot] = __builtin_amdgcn_mfma_f32_16x16x32_f16(a.h, hb0.h, zero4, 0, 0, 0);
            a.u = *(const uint4*)(Wfs[s] + ((size_t)((l*4 + ot)*2 + 1)*64 + lane)*4);
            d[ot] = __builtin_amdgcn_mfma_f32_16x16x32_f16(a.h, hb1.h, d[ot], 0, 0, 0);
        }
        #pragma unroll
        for (int ot = 0; ot < 4; ++ot) {
            uint p0 = pack2_f16(silu_f(d[ot][0]), silu_f(d[ot][1]));
            uint p1 = pack2_f16(silu_f(d[ot][2]), silu_f(d[ot][3]));
            uint* dst = &H[er][8*ot + 2*kb];
            dst[0] = p0; dst[1] = p1;
        }
    }

    // ---- stage 4: R = W4^T @ H, 4 ranks; pack f16x2; store via LDS ----
    FU hb0, hb1;
    hb0.u = *(const uint4*)&H[er][4*kb];
    hb1.u = *(const uint4*)&H[er][16 + 4*kb];
    #pragma unroll
    for (int ri = 0; ri < 4; ++ri) {
        #pragma unroll
        for (int otl = 0; otl < 4; ++otl) {
            int ot = ri*4 + otl;
            FU a;
            f32x4 d2;
            a.u = *(const uint4*)(Wf4 + ((size_t)((l*16 + ot)*2 + 0)*64 + lane)*4);
            d2 = __builtin_amdgcn_mfma_f32_16x16x32_f16(a.h, hb0.h, zero4, 0, 0, 0);
            a.u = *(const uint4*)(Wf4 + ((size_t)((l*16 + ot)*2 + 1)*64 + lane)*4);
            d2 = __builtin_amdgcn_mfma_f32_16x16x32_f16(a.h, hb1.h, d2, 0, 0, 0);
            uint p0 = pack2_f16(d2[0], d2[1]);
            uint p1 = pack2_f16(d2[2], d2[3]);
            uint* dst = &H[er][8*otl + 2*kb];   // reuse H as out-stage buffer
            dst[0] = p0; dst[1] = p1;
        }
        #pragma unroll
        for (int it = 0; it < 2; ++it) {
            int row  = it*8 + (lane >> 3);
            int col4 = (lane & 7) * 4;
            int eg   = e0 + row;
            if (eg < E) {
                *(uint4*)(Rpk + ((size_t)l*E + eg)*128 + ri*32 + col4) =
                    *(const uint4*)&H[row][col4];
            }
        }
    }
}

// ---------------- node gather + contraction + mix + readout ----------------
__global__ __launch_bounds__(256) void k_node(
    const uint*  __restrict__ Rpk,     // [E,128] u32 this layer (f16x2)
    const float* __restrict__ h0,      // [N,64] input features
    const int*   __restrict__ senders, // [E]
    const float* __restrict__ Yb,      // [E,40]
    const int*   __restrict__ offsets, // [N+1]
    const int*   __restrict__ elist,   // [E]
    const float* __restrict__ mixw,    // [4,64,64] (this layer)
    const float* __restrict__ readw,   // [64]      (this layer)
    float* __restrict__ h0n,           // [N,64]
    const float* __restrict__ eprev,   // [N] or null
    float* __restrict__ eout,          // [N]
    int N)
{
    int gtid = blockIdx.x * blockDim.x + threadIdx.x;
    int wave = gtid >> 6;
    int lane = threadIdx.x & 63;
    int w    = threadIdx.x >> 6;
    __shared__ float Bl[4][4][64];
    bool active = (wave < N);
    int n = active ? wave : 0;
    int half = lane & 1;
    int cpair = lane >> 1;

    float A[40];
    #pragma unroll
    for (int d = 0; d < 40; ++d) A[d] = 0.0f;

    if (active) {
        int beg = offsets[n], end = offsets[n+1];
        for (int i = beg; i < end; ++i) {
            int e = elist[i];
            int snd = senders[e];
            const float* Yr = Yb + (size_t)e*40;
            const uint*  Rr = Rpk + (size_t)e*128;
            float hj = h0[(size_t)snd*64 + lane];
            float t0 = unpk_f16(Rr[cpair],      half) * hj;
            float t1 = unpk_f16(Rr[32 + cpair], half) * hj;
            float t2 = unpk_f16(Rr[64 + cpair], half) * hj;
            float t3 = unpk_f16(Rr[96 + cpair], half) * hj;
            A[0] = fmaf(t0, Yr[0], A[0]);
            #pragma unroll
            for (int d = 0; d < 3; ++d)  A[1+d]  = fmaf(t1, Yr[1+d],  A[1+d]);
            #pragma unroll
            for (int d = 0; d < 9; ++d)  A[4+d]  = fmaf(t2, Yr[4+d],  A[4+d]);
            #pragma unroll
            for (int d = 0; d < 27; ++d) A[13+d] = fmaf(t3, Yr[13+d], A[13+d]);
        }
    }
    const float inv = 1.0f / 16.0f;  // AVG_NEIGH
    #pragma unroll
    for (int d = 0; d < 40; ++d) A[d] *= inv;

    float B0 = A[0];
    float B1 = 0.f, B2 = 0.f, B3 = 0.f;
    #pragma unroll
    for (int d = 0; d < 3; ++d)  B1 = fmaf(A[1+d],  A[1+d],  B1);
    #pragma unroll
    for (int d = 0; d < 9; ++d)  B2 = fmaf(A[4+d],  A[4+d],  B2);
    #pragma unroll
    for (int d = 0; d < 27; ++d) B3 = fmaf(A[13+d], A[13+d], B3);

    Bl[w][0][lane] = B0;
    Bl[w][1][lane] = B1;
    Bl[w][2][lane] = B2;
    Bl[w][3][lane] = B3;
    __syncthreads();

    if (active) {
        float acc = 0.0f;
        for (int ri = 0; ri < 4; ++ri) {
            #pragma unroll 8
            for (int j = 0; j < 64; ++j)
                acc = fmaf(Bl[w][ri][j], mixw[(ri*64 + j)*64 + lane], acc);
        }
        h0n[(size_t)n*64 + lane] = acc;

        float evl = acc * readw[lane];
        #pragma unroll
        for (int off = 1; off < 64; off <<= 1) evl += __shfl_xor(evl, off, 64);
        if (lane == 0) {
            float o = evl;
            if (eprev) o += eprev[n];
            eout[n] = o;
        }
    }
}

// ---------------------------------------------------------------------------
extern "C" void kernel_launch(void* const* d_in, const int* in_sizes, int n_in,
                              void* d_out, int out_size, void* d_ws, size_t ws_size,
                              hipStream_t stream)
{
    const int*   species   = (const int*)  d_in[0];
    const int*   senders   = (const int*)  d_in[1];
    const int*   receivers = (const int*)  d_in[2];
    const float* edge_vec  = (const float*)d_in[3];
    const float* embed_w   = (const float*)d_in[4];
    const float* rad_w1    = (const float*)d_in[5];
    const float* rad_w2    = (const float*)d_in[6];
    const float* rad_w3    = (const float*)d_in[7];
    const float* rad_w4    = (const float*)d_in[8];
    const float* mix_w     = (const float*)d_in[9];
    const float* read_w    = (const float*)d_in[10];

    int N = in_sizes[0];
    int E = in_sizes[1];
    float* out = (float*)d_out;

    char* ws = (char*)d_ws;
    size_t off = 0;
    auto alloc = [&](size_t bytes) -> char* {
        char* p = ws + off;
        off = (off + bytes + 255) & ~(size_t)255;
        return p;
    };
    uint*  rbh   = (uint*) alloc((size_t)E*4*sizeof(uint));
    float* Yb    = (float*)alloc((size_t)E*40*sizeof(float));
    float* h0a   = (float*)alloc((size_t)N*64*sizeof(float));
    float* h0b   = (float*)alloc((size_t)N*64*sizeof(float));
    float* ener  = (float*)alloc((size_t)N*sizeof(float));
    int* counts  = (int*)alloc((size_t)N*sizeof(int));
    int* offsets = (int*)alloc((size_t)(N+1)*sizeof(int));
    int* cursor  = (int*)alloc((size_t)N*sizeof(int));
    int* elist   = (int*)alloc((size_t)E*sizeof(int));
    uint* Wf1    = (uint*)alloc(2048*sizeof(uint));
    uint* Wf2    = (uint*)alloc(4096*sizeof(uint));
    uint* Wf3    = (uint*)alloc(4096*sizeof(uint));
    uint* Wf4    = (uint*)alloc(16384*sizeof(uint));
    uint* Rpk    = (uint*)alloc((size_t)2*E*128*sizeof(uint));

    hipMemsetAsync(counts, 0, (size_t)N*sizeof(int), stream);
    hipMemsetAsync(cursor, 0, (size_t)N*sizeof(int), stream);

    k_edge_basis<<<(E + 255)/256, 256, 0, stream>>>(edge_vec, rbh, Yb, E);
    k_prep_w<<<(26624 + 255)/256, 256, 0, stream>>>(
        rad_w1, rad_w2, rad_w3, rad_w4, Wf1, Wf2, Wf3, Wf4);
    k_hist<<<(E + 255)/256, 256, 0, stream>>>(receivers, counts, E);
    k_scan<<<1, 1024, 0, stream>>>(counts, offsets, N);
    k_scatter<<<(E + 255)/256, 256, 0, stream>>>(receivers, offsets, cursor, elist, E);
    k_sort_wave<<<((size_t)N*64 + 255)/256, 256, 0, stream>>>(offsets, elist, N);
    k_embed<<<((size_t)N*64 + 255)/256, 256, 0, stream>>>(species, embed_w, h0a, N*64);

    int tiles = (E + 15) / 16;
    int waves = 2 * tiles;
    k_mlp_mfma<<<(waves + 3)/4, 256, 0, stream>>>(
        rbh, Wf1, Wf2, Wf3, Wf4, Rpk, E, tiles);

    float* hcur = h0a;
    float* hnxt = h0b;
    for (int l = 0; l < 2; ++l) {
        uint* Rl = Rpk + (size_t)l * E * 128;
        k_node<<<((size_t)N*64 + 255)/256, 256, 0, stream>>>(
            Rl, hcur, senders, Yb, offsets, elist,
            mix_w + (size_t)l*4*64*64,
            read_w + (size_t)l*64,
            hnxt,
            (l == 0) ? nullptr : ener,
            (l == 0) ? ener : out,
            N);
        float* tmp = hcur; hcur = hnxt; hnxt = tmp;
    }
}

// Round 7
// 131.135 us; speedup vs baseline: 50.4478x; 1.5925x over previous
//
#include <hip/hip_runtime.h>
#include <math.h>

// ---------------------------------------------------------------------------
// TACE (MACE-style equivariant GNN) forward on MI355X.
// N=5000 nodes, E=80000 edges, C=64, 2 layers, ranks 0..3 (dims 1,3,9,27).
//
// R7: k_node latency fix.
//  - Y basis eliminated: reconstructed per-edge from rhat via unique
//    symmetric-tensor components (a1[3],a2[6],a3[10]; multiplicity weights
//    and norm constants {3,5,7} applied at the invariant (B) stage).
//  - Rpk rank-interleaved [E][32pair][4rank]: one uint4 load per edge/lane.
//  - Edge loop unrolled x4, elist/senders/rhat via scalar loads.
//  - k_hist fused into k_edge_basis.
// MLP stays on matrix pipe (R5/R6 structure).
// ---------------------------------------------------------------------------

#define PI_F 3.14159265358979323846f

typedef _Float16 f16x8 __attribute__((ext_vector_type(8)));
typedef float f32x4 __attribute__((ext_vector_type(4)));

union FU { uint4 u; f16x8 h; };

__device__ __forceinline__ float silu_f(float x) {
    return x / (1.0f + expf(-x));
}

__device__ __forceinline__ uint pack2_f16(float a, float b) {
    unsigned short lo = __builtin_bit_cast(unsigned short, (_Float16)a);
    unsigned short hi = __builtin_bit_cast(unsigned short, (_Float16)b);
    return (uint)lo | ((uint)hi << 16);
}

__device__ __forceinline__ float unpk_f16(uint u, int hi) {
    unsigned short s = hi ? (unsigned short)(u >> 16) : (unsigned short)(u & 0xffff);
    return (float)__builtin_bit_cast(_Float16, s);
}

// ---------------- edge basis (rb f16, rhat) + receiver histogram ----------
__global__ void k_edge_basis(const float* __restrict__ ev,
                             const int* __restrict__ recv,
                             uint*  __restrict__ rbh,     // [E,4] u32 (8 f16)
                             float* __restrict__ rhat4,   // [E,4]
                             int*   __restrict__ counts,
                             int E)
{
    int e = blockIdx.x * blockDim.x + threadIdx.x;
    if (e >= E) return;
    float vx = ev[3*e+0], vy = ev[3*e+1], vz = ev[3*e+2];
    float r2 = vx*vx + vy*vy + vz*vz + 1e-12f;
    float r  = sqrtf(r2);
    float x  = r * 0.2f;                   // r / CUTOFF
    float x2 = x*x;
    float x5 = x2*x2*x;
    float env = 1.0f + x5*(-21.0f + x*(35.0f - 15.0f*x));
    if (x >= 1.0f) env = 0.0f;
    float pref = 0.632455532033675866f / r * env;   // sqrt(2/5)/r * env
    float pix  = PI_F * x;
    float bas[8];
    #pragma unroll
    for (int k = 0; k < 8; ++k) bas[k] = pref * sinf((float)(k+1) * pix);
    uint* o = rbh + (size_t)e*4;
    #pragma unroll
    for (int k = 0; k < 4; ++k) o[k] = pack2_f16(bas[2*k], bas[2*k+1]);

    float ir = 1.0f / r;
    float4 rh;
    rh.x = vx*ir; rh.y = vy*ir; rh.z = vz*ir; rh.w = 0.0f;
    *(float4*)(rhat4 + (size_t)e*4) = rh;

    atomicAdd(&counts[recv[e]], 1);
}

// ---------------- CSR build ----------------
// 1024-thread single-block exclusive scan, wave-shuffle based
__global__ void k_scan(const int* __restrict__ counts, int* __restrict__ offsets, int N)
{
    __shared__ int wsum[16];
    __shared__ int basev;
    int lane = threadIdx.x & 63;
    int w    = threadIdx.x >> 6;
    if (threadIdx.x == 0) basev = 0;
    __syncthreads();
    for (int start = 0; start < N; start += 1024) {
        int i = start + (int)threadIdx.x;
        int v = (i < N) ? counts[i] : 0;
        int s = v;
        #pragma unroll
        for (int off = 1; off < 64; off <<= 1) {
            int t = __shfl_up(s, off, 64);
            if (lane >= off) s += t;
        }
        if (lane == 63) wsum[w] = s;
        __syncthreads();
        int wbase = 0;
        {
            int ws = (lane < 16) ? wsum[lane] : 0;
            #pragma unroll
            for (int off = 1; off < 16; off <<= 1) {
                int t = __shfl_up(ws, off, 64);
                if (lane >= off) ws += t;
            }
            int excl = __shfl(ws, w - 1, 64);
            wbase = (w == 0) ? 0 : excl;
        }
        if (i < N) offsets[i] = basev + wbase + s - v;   // exclusive
        __syncthreads();
        if (threadIdx.x == 1023) basev += wbase + s;
        __syncthreads();
    }
    if (threadIdx.x == 0) offsets[N] = basev;
}

__global__ void k_scatter(const int* __restrict__ recv,
                          const int* __restrict__ offsets,
                          int* __restrict__ cursor,
                          int* __restrict__ elist, int E)
{
    int e = blockIdx.x * blockDim.x + threadIdx.x;
    if (e >= E) return;
    int r = recv[e];
    int p = atomicAdd(&cursor[r], 1);
    elist[offsets[r] + p] = e;
}

// wave-parallel rank sort: one wave per node (deterministic ascending order)
__global__ __launch_bounds__(256) void k_sort_wave(
    const int* __restrict__ offsets, int* __restrict__ elist, int N)
{
    int lane = threadIdx.x & 63;
    int node = (blockIdx.x * blockDim.x + threadIdx.x) >> 6;
    if (node >= N) return;
    int beg = offsets[node], end = offsets[node+1];
    int d = end - beg;
    if (d <= 1) return;
    if (d <= 64) {
        int v = (lane < d) ? elist[beg + lane] : 0x7fffffff;
        int rank = 0;
        #pragma unroll 8
        for (int j = 0; j < 64; ++j) {
            int vj = __shfl(v, j, 64);
            rank += (vj < v) ? 1 : 0;
        }
        if (lane < d) elist[beg + rank] = v;
    } else {
        if (lane == 0) {
            for (int i = beg + 1; i < end; ++i) {
                int v = elist[i];
                int j = i - 1;
                while (j >= beg && elist[j] > v) { elist[j+1] = elist[j]; --j; }
                elist[j+1] = v;
            }
        }
    }
}

__global__ void k_embed(const int* __restrict__ species,
                        const float* __restrict__ embw,
                        float* __restrict__ h0, int NC)
{
    int i = blockIdx.x * blockDim.x + threadIdx.x;
    if (i >= NC) return;
    int n = i >> 6, c = i & 63;
    h0[i] = embw[species[n]*64 + c];
}

// ---------------- weight prep: fragment-ordered f16 ----------------
__global__ void k_prep_w(const float* __restrict__ rw1,   // [2,8,64]
                         const float* __restrict__ rw2,   // [2,64,64]
                         const float* __restrict__ rw3,   // [2,64,64]
                         const float* __restrict__ rw4,   // [2,64,256]
                         uint* __restrict__ Wf1, uint* __restrict__ Wf2,
                         uint* __restrict__ Wf3, uint* __restrict__ Wf4)
{
    int tid = blockIdx.x * blockDim.x + threadIdx.x;
    if (tid < 2048) {
        int reg = tid & 3, lane = (tid >> 2) & 63, ot = (tid >> 8) & 3, l = tid >> 10;
        int out = 16*ot + (lane & 15);
        int k   = 8*(lane >> 4) + 2*reg;
        float lo = (k   < 8) ? rw1[l*512 + k*64 + out]     : 0.0f;
        float hi = (k+1 < 8) ? rw1[l*512 + (k+1)*64 + out] : 0.0f;
        Wf1[tid] = pack2_f16(lo, hi);
        return;
    }
    int t = tid - 2048;
    if (t < 4096) {
        int reg = t & 3, lane = (t >> 2) & 63, kt = (t >> 8) & 1, ot = (t >> 9) & 3, l = t >> 11;
        int out = 16*ot + (lane & 15);
        int k   = 32*kt + 8*(lane >> 4) + 2*reg;
        Wf2[t] = pack2_f16(rw2[l*4096 + k*64 + out], rw2[l*4096 + (k+1)*64 + out]);
        return;
    }
    t -= 4096;
    if (t < 4096) {
        int reg = t & 3, lane = (t >> 2) & 63, kt = (t >> 8) & 1, ot = (t >> 9) & 3, l = t >> 11;
        int out = 16*ot + (lane & 15);
        int k   = 32*kt + 8*(lane >> 4) + 2*reg;
        Wf3[t] = pack2_f16(rw3[l*4096 + k*64 + out], rw3[l*4096 + (k+1)*64 + out]);
        return;
    }
    t -= 4096;
    if (t < 16384) {
        int reg = t & 3, lane = (t >> 2) & 63, kt = (t >> 8) & 1, ot = (t >> 9) & 15, l = t >> 13;
        int out = 16*ot + (lane & 15);   // column in [64,256]
        int k   = 32*kt + 8*(lane >> 4) + 2*reg;
        Wf4[t] = pack2_f16(rw4[l*16384 + k*256 + out], rw4[l*16384 + (k+1)*256 + out]);
    }
}

// ---------------- radial MLP via MFMA ----------------
// One wave per (layer, 16-edge tile). H staged in wave-local LDS [16][132]
// u32 (stages 1-3 use cols 0..31; stage 4 builds rank-interleaved row
// [pair*4 + rank] in cols 0..127, flushed coalesced).
__global__ __launch_bounds__(256) void k_mlp_mfma(
    const uint* __restrict__ rbh,    // [E,4] u32 (8 f16)
    const uint* __restrict__ Wf1, const uint* __restrict__ Wf2,
    const uint* __restrict__ Wf3, const uint* __restrict__ Wf4,
    uint* __restrict__ Rpk,          // [2,E,128] u32, rank-interleaved
    int E, int tiles)
{
    __shared__ __align__(16) uint Hl[4][16][132];
    int lane = threadIdx.x & 63;
    int w    = threadIdx.x >> 6;
    int wid  = blockIdx.x * 4 + w;
    if (wid >= 2 * tiles) return;
    int l    = wid / tiles;
    int tile = wid % tiles;
    int e0   = tile * 16;

    uint (*H)[132] = Hl[w];
    int er = lane & 15;      // edge-in-tile (B col / D col)
    int kb = lane >> 4;      // k-group / row-group

    f32x4 zero4 = {0.f, 0.f, 0.f, 0.f};

    // ---- stage 1: D = W1^T @ rb ----
    FU b;
    if (kb == 0) {
        int e = e0 + er;
        if (e < E) b.u = *(const uint4*)(rbh + (size_t)e*4);
        else       b.u = make_uint4(0,0,0,0);
    } else {
        b.u = make_uint4(0,0,0,0);
    }
    f32x4 d[4];
    #pragma unroll
    for (int ot = 0; ot < 4; ++ot) {
        FU a;
        a.u = *(const uint4*)(Wf1 + ((size_t)(l*4 + ot)*64 + lane)*4);
        d[ot] = __builtin_amdgcn_mfma_f32_16x16x32_f16(a.h, b.h, zero4, 0, 0, 0);
    }
    #pragma unroll
    for (int ot = 0; ot < 4; ++ot) {
        uint p0 = pack2_f16(silu_f(d[ot][0]), silu_f(d[ot][1]));
        uint p1 = pack2_f16(silu_f(d[ot][2]), silu_f(d[ot][3]));
        uint* dst = &H[er][8*ot + 2*kb];
        dst[0] = p0; dst[1] = p1;
    }

    // ---- stages 2,3: D = W^T @ H ----
    const uint* Wfs[2] = { Wf2, Wf3 };
    #pragma unroll
    for (int s = 0; s < 2; ++s) {
        FU hb0, hb1;
        hb0.u = *(const uint4*)&H[er][4*kb];
        hb1.u = *(const uint4*)&H[er][16 + 4*kb];
        #pragma unroll
        for (int ot = 0; ot < 4; ++ot) {
            FU a;
            a.u = *(const uint4*)(Wfs[s] + ((size_t)((l*4 + ot)*2 + 0)*64 + lane)*4);
            d[ot] = __builtin_amdgcn_mfma_f32_16x16x32_f16(a.h, hb0.h, zero4, 0, 0, 0);
            a.u = *(const uint4*)(Wfs[s] + ((size_t)((l*4 + ot)*2 + 1)*64 + lane)*4);
            d[ot] = __builtin_amdgcn_mfma_f32_16x16x32_f16(a.h, hb1.h, d[ot], 0, 0, 0);
        }
        #pragma unroll
        for (int ot = 0; ot < 4; ++ot) {
            uint p0 = pack2_f16(silu_f(d[ot][0]), silu_f(d[ot][1]));
            uint p1 = pack2_f16(silu_f(d[ot][2]), silu_f(d[ot][3]));
            uint* dst = &H[er][8*ot + 2*kb];
            dst[0] = p0; dst[1] = p1;
        }
    }

    // ---- stage 4: R = W4^T @ H; rank-interleaved staging; coalesced flush --
    FU hb0, hb1;
    hb0.u = *(const uint4*)&H[er][4*kb];
    hb1.u = *(const uint4*)&H[er][16 + 4*kb];
    #pragma unroll
    for (int ri = 0; ri < 4; ++ri) {
        #pragma unroll
        for (int otl = 0; otl < 4; ++otl) {
            int ot = ri*4 + otl;
            FU a;
            f32x4 d2;
            a.u = *(const uint4*)(Wf4 + ((size_t)((l*16 + ot)*2 + 0)*64 + lane)*4);
            d2 = __builtin_amdgcn_mfma_f32_16x16x32_f16(a.h, hb0.h, zero4, 0, 0, 0);
            a.u = *(const uint4*)(Wf4 + ((size_t)((l*16 + ot)*2 + 1)*64 + lane)*4);
            d2 = __builtin_amdgcn_mfma_f32_16x16x32_f16(a.h, hb1.h, d2, 0, 0, 0);
            // channel pair p covers channels {2p,2p+1} of rank ri
            int p = otl*8 + kb*2;
            H[er][(p  )*4 + ri] = pack2_f16(d2[0], d2[1]);
            H[er][(p+1)*4 + ri] = pack2_f16(d2[2], d2[3]);
        }
    }
    // flush 16 rows x 128 u32, coalesced
    #pragma unroll
    for (int it = 0; it < 8; ++it) {
        int f   = it*64 + lane;
        int row = f >> 5;
        int q4  = (f & 31) * 4;
        int eg  = e0 + row;
        if (eg < E)
            *(uint4*)(Rpk + ((size_t)l*E + eg)*128 + q4) = *(const uint4*)&H[row][q4];
    }
}

// ---------------- node gather + contraction + mix + readout ----------------
// One wave per node. Unique-component accumulators (a0,a1[3],a2[6],a3[10]);
// angular basis rebuilt from rhat per edge. Edge loop unrolled x4.
__global__ __launch_bounds__(256) void k_node(
    const uint*  __restrict__ Rpk,     // [E,128] u32 this layer (rank-interleaved)
    const float* __restrict__ h0,      // [N,64]
    const int*   __restrict__ senders, // [E]
    const float* __restrict__ rhat4,   // [E,4]
    const int*   __restrict__ offsets, // [N+1]
    const int*   __restrict__ elist,   // [E]
    const float* __restrict__ mixw,    // [4,64,64] (this layer)
    const float* __restrict__ readw,   // [64]      (this layer)
    float* __restrict__ h0n,           // [N,64]
    const float* __restrict__ eprev,   // [N] or null
    float* __restrict__ eout,          // [N]
    int N)
{
    int gtid = blockIdx.x * blockDim.x + threadIdx.x;
    int wave = gtid >> 6;
    int lane = threadIdx.x & 63;
    int w    = threadIdx.x >> 6;
    __shared__ float Bl[4][4][64];
    bool active = (wave < N);
    int n = active ? wave : 0;
    int half  = lane & 1;
    int cpair = lane >> 1;

    float a0 = 0.f;
    float a1[3]  = {0.f,0.f,0.f};
    float a2[6]  = {0.f,0.f,0.f,0.f,0.f,0.f};
    float a3[10] = {0.f,0.f,0.f,0.f,0.f,0.f,0.f,0.f,0.f,0.f};

    auto accum = [&](float x, float y, float z, float hj, uint4 qv) {
        float t0 = unpk_f16(qv.x, half) * hj;
        float t1 = unpk_f16(qv.y, half) * hj;
        float t2 = unpk_f16(qv.z, half) * hj;
        float t3 = unpk_f16(qv.w, half) * hj;
        a0 += t0;
        a1[0] = fmaf(t1, x, a1[0]);
        a1[1] = fmaf(t1, y, a1[1]);
        a1[2] = fmaf(t1, z, a1[2]);
        float qxx = x*x, qxy = x*y, qxz = x*z, qyy = y*y, qyz = y*z, qzz = z*z;
        a2[0] = fmaf(t2, qxx, a2[0]);
        a2[1] = fmaf(t2, qxy, a2[1]);
        a2[2] = fmaf(t2, qxz, a2[2]);
        a2[3] = fmaf(t2, qyy, a2[3]);
        a2[4] = fmaf(t2, qyz, a2[4]);
        a2[5] = fmaf(t2, qzz, a2[5]);
        float u0 = t3*qxx, u1 = t3*qxy, u3 = t3*qyy, u5 = t3*qzz;
        a3[0] = fmaf(u0, x, a3[0]);  // xxx
        a3[1] = fmaf(u0, y, a3[1]);  // xxy
        a3[2] = fmaf(u0, z, a3[2]);  // xxz
        a3[3] = fmaf(u3, x, a3[3]);  // xyy
        a3[4] = fmaf(u1, z, a3[4]);  // xyz
        a3[5] = fmaf(u5, x, a3[5]);  // xzz
        a3[6] = fmaf(u3, y, a3[6]);  // yyy
        a3[7] = fmaf(u3, z, a3[7]);  // yyz
        a3[8] = fmaf(u5, y, a3[8]);  // yzz
        a3[9] = fmaf(u5, z, a3[9]);  // zzz
    };

    if (active) {
        int beg = __builtin_amdgcn_readfirstlane(offsets[n]);
        int end = __builtin_amdgcn_readfirstlane(offsets[n+1]);
        int i = beg;
        for (; i + 4 <= end; i += 4) {
            int   e_[4], sn_[4];
            #pragma unroll
            for (int k = 0; k < 4; ++k) {
                e_[k]  = __builtin_amdgcn_readfirstlane(elist[i+k]);
                sn_[k] = __builtin_amdgcn_readfirstlane(senders[e_[k]]);
            }
            float4 rh_[4]; float hj_[4]; uint4 q_[4];
            #pragma unroll
            for (int k = 0; k < 4; ++k) {
                rh_[k] = *(const float4*)(rhat4 + (size_t)e_[k]*4);
                hj_[k] = h0[(size_t)sn_[k]*64 + lane];
                q_[k]  = *(const uint4*)(Rpk + (size_t)e_[k]*128 + cpair*4);
            }
            #pragma unroll
            for (int k = 0; k < 4; ++k)
                accum(rh_[k].x, rh_[k].y, rh_[k].z, hj_[k], q_[k]);
        }
        for (; i < end; ++i) {
            int e   = __builtin_amdgcn_readfirstlane(elist[i]);
            int snd = __builtin_amdgcn_readfirstlane(senders[e]);
            float4 rh = *(const float4*)(rhat4 + (size_t)e*4);
            float  hj = h0[(size_t)snd*64 + lane];
            uint4  qv = *(const uint4*)(Rpk + (size_t)e*128 + cpair*4);
            accum(rh.x, rh.y, rh.z, hj, qv);
        }
    }

    // invariants: B_r = (2r+1)/256 * sum over full tensor (multiplicity wts)
    float B0 = a0 * 0.0625f;                       // A0/16 (linear, rank 0)
    float s1 = a1[0]*a1[0] + a1[1]*a1[1] + a1[2]*a1[2];
    float B1 = s1 * (3.0f/256.0f);
    float s2 = a2[0]*a2[0] + a2[3]*a2[3] + a2[5]*a2[5]
             + 2.0f*(a2[1]*a2[1] + a2[2]*a2[2] + a2[4]*a2[4]);
    float B2 = s2 * (5.0f/256.0f);
    float s3 = a3[0]*a3[0] + a3[6]*a3[6] + a3[9]*a3[9]
             + 3.0f*(a3[1]*a3[1] + a3[2]*a3[2] + a3[3]*a3[3]
                   + a3[5]*a3[5] + a3[7]*a3[7] + a3[8]*a3[8])
             + 6.0f*a3[4]*a3[4];
    float B3 = s3 * (7.0f/256.0f);

    Bl[w][0][lane] = B0;
    Bl[w][1][lane] = B1;
    Bl[w][2][lane] = B2;
    Bl[w][3][lane] = B3;
    __syncthreads();

    if (active) {
        float acc = 0.0f;
        for (int ri = 0; ri < 4; ++ri) {
            #pragma unroll 8
            for (int j = 0; j < 64; ++j)
                acc = fmaf(Bl[w][ri][j], mixw[(ri*64 + j)*64 + lane], acc);
        }
        h0n[(size_t)n*64 + lane] = acc;

        float evl = acc * readw[lane];
        #pragma unroll
        for (int off = 1; off < 64; off <<= 1) evl += __shfl_xor(evl, off, 64);
        if (lane == 0) {
            float o = evl;
            if (eprev) o += eprev[n];
            eout[n] = o;
        }
    }
}

// ---------------------------------------------------------------------------
extern "C" void kernel_launch(void* const* d_in, const int* in_sizes, int n_in,
                              void* d_out, int out_size, void* d_ws, size_t ws_size,
                              hipStream_t stream)
{
    const int*   species   = (const int*)  d_in[0];
    const int*   senders   = (const int*)  d_in[1];
    const int*   receivers = (const int*)  d_in[2];
    const float* edge_vec  = (const float*)d_in[3];
    const float* embed_w   = (const float*)d_in[4];
    const float* rad_w1    = (const float*)d_in[5];
    const float* rad_w2    = (const float*)d_in[6];
    const float* rad_w3    = (const float*)d_in[7];
    const float* rad_w4    = (const float*)d_in[8];
    const float* mix_w     = (const float*)d_in[9];
    const float* read_w    = (const float*)d_in[10];

    int N = in_sizes[0];
    int E = in_sizes[1];
    float* out = (float*)d_out;

    char* ws = (char*)d_ws;
    size_t off = 0;
    auto alloc = [&](size_t bytes) -> char* {
        char* p = ws + off;
        off = (off + bytes + 255) & ~(size_t)255;
        return p;
    };
    uint*  rbh   = (uint*) alloc((size_t)E*4*sizeof(uint));
    float* rhat4 = (float*)alloc((size_t)E*4*sizeof(float));
    float* h0a   = (float*)alloc((size_t)N*64*sizeof(float));
    float* h0b   = (float*)alloc((size_t)N*64*sizeof(float));
    float* ener  = (float*)alloc((size_t)N*sizeof(float));
    int* counts  = (int*)alloc((size_t)N*sizeof(int));
    int* offsets = (int*)alloc((size_t)(N+1)*sizeof(int));
    int* cursor  = (int*)alloc((size_t)N*sizeof(int));
    int* elist   = (int*)alloc((size_t)E*sizeof(int));
    uint* Wf1    = (uint*)alloc(2048*sizeof(uint));
    uint* Wf2    = (uint*)alloc(4096*sizeof(uint));
    uint* Wf3    = (uint*)alloc(4096*sizeof(uint));
    uint* Wf4    = (uint*)alloc(16384*sizeof(uint));
    uint* Rpk    = (uint*)alloc((size_t)2*E*128*sizeof(uint));

    hipMemsetAsync(counts, 0, (size_t)N*sizeof(int), stream);
    hipMemsetAsync(cursor, 0, (size_t)N*sizeof(int), stream);

    k_edge_basis<<<(E + 255)/256, 256, 0, stream>>>(
        edge_vec, receivers, rbh, rhat4, counts, E);
    k_prep_w<<<(26624 + 255)/256, 256, 0, stream>>>(
        rad_w1, rad_w2, rad_w3, rad_w4, Wf1, Wf2, Wf3, Wf4);
    k_scan<<<1, 1024, 0, stream>>>(counts, offsets, N);
    k_scatter<<<(E + 255)/256, 256, 0, stream>>>(receivers, offsets, cursor, elist, E);
    k_sort_wave<<<((size_t)N*64 + 255)/256, 256, 0, stream>>>(offsets, elist, N);
    k_embed<<<((size_t)N*64 + 255)/256, 256, 0, stream>>>(species, embed_w, h0a, N*64);

    int tiles = (E + 15) / 16;
    int waves = 2 * tiles;
    k_mlp_mfma<<<(waves + 3)/4, 256, 0, stream>>>(
        rbh, Wf1, Wf2, Wf3, Wf4, Rpk, E, tiles);

    float* hcur = h0a;
    float* hnxt = h0b;
    for (int l = 0; l < 2; ++l) {
        uint* Rl = Rpk + (size_t)l * E * 128;
        k_node<<<((size_t)N*64 + 255)/256, 256, 0, stream>>>(
            Rl, hcur, senders, rhat4, offsets, elist,
            mix_w + (size_t)l*4*64*64,
            read_w + (size_t)l*64,
            hnxt,
            (l == 0) ? nullptr : ener,
            (l == 0) ? ener : out,
            N);
        float* tmp = hcur; hcur = hnxt; hnxt = tmp;
    }
}

// Round 8
// 118.443 us; speedup vs baseline: 55.8537x; 1.1072x over previous
//
#include <hip/hip_runtime.h>
#include <math.h>

// ---------------------------------------------------------------------------
// TACE (MACE-style equivariant GNN) forward on MI355X.
// N=5000 nodes, E=80000 edges, C=64, 2 layers, ranks 0..3 (dims 1,3,9,27).
//
// R8: VALU-epilogue diet for the MFMA MLP (was VALUBusy 65% / MfmaUtil 7%):
//  - silu via native v_exp/v_rcp (5 VALU vs ~20 with libm expf + exact div)
//  - f16 packing via v_cvt_pkrtz (1 VALU vs 3)
//  - k_edge_basis sinf -> __sinf (native; result stored f16 anyway)
// Structure unchanged from R7.
// ---------------------------------------------------------------------------

#define PI_F 3.14159265358979323846f
#define LOG2E_F 1.44269504088896340736f

typedef _Float16 f16x8 __attribute__((ext_vector_type(8)));
typedef _Float16 f16x2 __attribute__((ext_vector_type(2)));
typedef float f32x4 __attribute__((ext_vector_type(4)));

union FU { uint4 u; f16x8 h; };

__device__ __forceinline__ float silu_f(float x) {
    // x * rcp(1 + 2^(-x*log2e)) : v_mul, v_exp, v_add, v_rcp, v_mul
    float e = __builtin_amdgcn_exp2f(-LOG2E_F * x);
    return x * __builtin_amdgcn_rcpf(1.0f + e);
}

__device__ __forceinline__ uint pack2_f16(float a, float b) {
    return __builtin_bit_cast(uint, __builtin_amdgcn_cvt_pkrtz(a, b));
}

__device__ __forceinline__ float unpk_f16(uint u, int hi) {
    unsigned short s = hi ? (unsigned short)(u >> 16) : (unsigned short)(u & 0xffff);
    return (float)__builtin_bit_cast(_Float16, s);
}

// ---------------- edge basis (rb f16, rhat) + receiver histogram ----------
__global__ void k_edge_basis(const float* __restrict__ ev,
                             const int* __restrict__ recv,
                             uint*  __restrict__ rbh,     // [E,4] u32 (8 f16)
                             float* __restrict__ rhat4,   // [E,4]
                             int*   __restrict__ counts,
                             int E)
{
    int e = blockIdx.x * blockDim.x + threadIdx.x;
    if (e >= E) return;
    float vx = ev[3*e+0], vy = ev[3*e+1], vz = ev[3*e+2];
    float r2 = vx*vx + vy*vy + vz*vz + 1e-12f;
    float r  = sqrtf(r2);
    float x  = r * 0.2f;                   // r / CUTOFF
    float x2 = x*x;
    float x5 = x2*x2*x;
    float env = 1.0f + x5*(-21.0f + x*(35.0f - 15.0f*x));
    if (x >= 1.0f) env = 0.0f;
    float pref = 0.632455532033675866f / r * env;   // sqrt(2/5)/r * env
    float pix  = PI_F * x;
    float bas[8];
    #pragma unroll
    for (int k = 0; k < 8; ++k) bas[k] = pref * __sinf((float)(k+1) * pix);
    uint* o = rbh + (size_t)e*4;
    #pragma unroll
    for (int k = 0; k < 4; ++k) o[k] = pack2_f16(bas[2*k], bas[2*k+1]);

    float ir = 1.0f / r;
    float4 rh;
    rh.x = vx*ir; rh.y = vy*ir; rh.z = vz*ir; rh.w = 0.0f;
    *(float4*)(rhat4 + (size_t)e*4) = rh;

    atomicAdd(&counts[recv[e]], 1);
}

// ---------------- CSR build ----------------
__global__ void k_scan(const int* __restrict__ counts, int* __restrict__ offsets, int N)
{
    __shared__ int wsum[16];
    __shared__ int basev;
    int lane = threadIdx.x & 63;
    int w    = threadIdx.x >> 6;
    if (threadIdx.x == 0) basev = 0;
    __syncthreads();
    for (int start = 0; start < N; start += 1024) {
        int i = start + (int)threadIdx.x;
        int v = (i < N) ? counts[i] : 0;
        int s = v;
        #pragma unroll
        for (int off = 1; off < 64; off <<= 1) {
            int t = __shfl_up(s, off, 64);
            if (lane >= off) s += t;
        }
        if (lane == 63) wsum[w] = s;
        __syncthreads();
        int wbase = 0;
        {
            int ws = (lane < 16) ? wsum[lane] : 0;
            #pragma unroll
            for (int off = 1; off < 16; off <<= 1) {
                int t = __shfl_up(ws, off, 64);
                if (lane >= off) ws += t;
            }
            int excl = __shfl(ws, w - 1, 64);
            wbase = (w == 0) ? 0 : excl;
        }
        if (i < N) offsets[i] = basev + wbase + s - v;   // exclusive
        __syncthreads();
        if (threadIdx.x == 1023) basev += wbase + s;
        __syncthreads();
    }
    if (threadIdx.x == 0) offsets[N] = basev;
}

__global__ void k_scatter(const int* __restrict__ recv,
                          const int* __restrict__ offsets,
                          int* __restrict__ cursor,
                          int* __restrict__ elist, int E)
{
    int e = blockIdx.x * blockDim.x + threadIdx.x;
    if (e >= E) return;
    int r = recv[e];
    int p = atomicAdd(&cursor[r], 1);
    elist[offsets[r] + p] = e;
}

// wave-parallel rank sort: one wave per node (deterministic ascending order)
__global__ __launch_bounds__(256) void k_sort_wave(
    const int* __restrict__ offsets, int* __restrict__ elist, int N)
{
    int lane = threadIdx.x & 63;
    int node = (blockIdx.x * blockDim.x + threadIdx.x) >> 6;
    if (node >= N) return;
    int beg = offsets[node], end = offsets[node+1];
    int d = end - beg;
    if (d <= 1) return;
    if (d <= 64) {
        int v = (lane < d) ? elist[beg + lane] : 0x7fffffff;
        int rank = 0;
        #pragma unroll 8
        for (int j = 0; j < 64; ++j) {
            int vj = __shfl(v, j, 64);
            rank += (vj < v) ? 1 : 0;
        }
        if (lane < d) elist[beg + rank] = v;
    } else {
        if (lane == 0) {
            for (int i = beg + 1; i < end; ++i) {
                int v = elist[i];
                int j = i - 1;
                while (j >= beg && elist[j] > v) { elist[j+1] = elist[j]; --j; }
                elist[j+1] = v;
            }
        }
    }
}

__global__ void k_embed(const int* __restrict__ species,
                        const float* __restrict__ embw,
                        float* __restrict__ h0, int NC)
{
    int i = blockIdx.x * blockDim.x + threadIdx.x;
    if (i >= NC) return;
    int n = i >> 6, c = i & 63;
    h0[i] = embw[species[n]*64 + c];
}

// ---------------- weight prep: fragment-ordered f16 ----------------
__global__ void k_prep_w(const float* __restrict__ rw1,   // [2,8,64]
                         const float* __restrict__ rw2,   // [2,64,64]
                         const float* __restrict__ rw3,   // [2,64,64]
                         const float* __restrict__ rw4,   // [2,64,256]
                         uint* __restrict__ Wf1, uint* __restrict__ Wf2,
                         uint* __restrict__ Wf3, uint* __restrict__ Wf4)
{
    int tid = blockIdx.x * blockDim.x + threadIdx.x;
    if (tid < 2048) {
        int reg = tid & 3, lane = (tid >> 2) & 63, ot = (tid >> 8) & 3, l = tid >> 10;
        int out = 16*ot + (lane & 15);
        int k   = 8*(lane >> 4) + 2*reg;
        float lo = (k   < 8) ? rw1[l*512 + k*64 + out]     : 0.0f;
        float hi = (k+1 < 8) ? rw1[l*512 + (k+1)*64 + out] : 0.0f;
        Wf1[tid] = pack2_f16(lo, hi);
        return;
    }
    int t = tid - 2048;
    if (t < 4096) {
        int reg = t & 3, lane = (t >> 2) & 63, kt = (t >> 8) & 1, ot = (t >> 9) & 3, l = t >> 11;
        int out = 16*ot + (lane & 15);
        int k   = 32*kt + 8*(lane >> 4) + 2*reg;
        Wf2[t] = pack2_f16(rw2[l*4096 + k*64 + out], rw2[l*4096 + (k+1)*64 + out]);
        return;
    }
    t -= 4096;
    if (t < 4096) {
        int reg = t & 3, lane = (t >> 2) & 63, kt = (t >> 8) & 1, ot = (t >> 9) & 3, l = t >> 11;
        int out = 16*ot + (lane & 15);
        int k   = 32*kt + 8*(lane >> 4) + 2*reg;
        Wf3[t] = pack2_f16(rw3[l*4096 + k*64 + out], rw3[l*4096 + (k+1)*64 + out]);
        return;
    }
    t -= 4096;
    if (t < 16384) {
        int reg = t & 3, lane = (t >> 2) & 63, kt = (t >> 8) & 1, ot = (t >> 9) & 15, l = t >> 13;
        int out = 16*ot + (lane & 15);   // column in [64,256]
        int k   = 32*kt + 8*(lane >> 4) + 2*reg;
        Wf4[t] = pack2_f16(rw4[l*16384 + k*256 + out], rw4[l*16384 + (k+1)*256 + out]);
    }
}

// ---------------- radial MLP via MFMA ----------------
__global__ __launch_bounds__(256) void k_mlp_mfma(
    const uint* __restrict__ rbh,    // [E,4] u32 (8 f16)
    const uint* __restrict__ Wf1, const uint* __restrict__ Wf2,
    const uint* __restrict__ Wf3, const uint* __restrict__ Wf4,
    uint* __restrict__ Rpk,          // [2,E,128] u32, rank-interleaved
    int E, int tiles)
{
    __shared__ __align__(16) uint Hl[4][16][132];
    int lane = threadIdx.x & 63;
    int w    = threadIdx.x >> 6;
    int wid  = blockIdx.x * 4 + w;
    if (wid >= 2 * tiles) return;
    int l    = wid / tiles;
    int tile = wid % tiles;
    int e0   = tile * 16;

    uint (*H)[132] = Hl[w];
    int er = lane & 15;      // edge-in-tile (B col / D col)
    int kb = lane >> 4;      // k-group / row-group

    f32x4 zero4 = {0.f, 0.f, 0.f, 0.f};

    // ---- stage 1: D = W1^T @ rb ----
    FU b;
    if (kb == 0) {
        int e = e0 + er;
        if (e < E) b.u = *(const uint4*)(rbh + (size_t)e*4);
        else       b.u = make_uint4(0,0,0,0);
    } else {
        b.u = make_uint4(0,0,0,0);
    }
    f32x4 d[4];
    #pragma unroll
    for (int ot = 0; ot < 4; ++ot) {
        FU a;
        a.u = *(const uint4*)(Wf1 + ((size_t)(l*4 + ot)*64 + lane)*4);
        d[ot] = __builtin_amdgcn_mfma_f32_16x16x32_f16(a.h, b.h, zero4, 0, 0, 0);
    }
    #pragma unroll
    for (int ot = 0; ot < 4; ++ot) {
        uint p0 = pack2_f16(silu_f(d[ot][0]), silu_f(d[ot][1]));
        uint p1 = pack2_f16(silu_f(d[ot][2]), silu_f(d[ot][3]));
        uint* dst = &H[er][8*ot + 2*kb];
        dst[0] = p0; dst[1] = p1;
    }

    // ---- stages 2,3: D = W^T @ H ----
    const uint* Wfs[2] = { Wf2, Wf3 };
    #pragma unroll
    for (int s = 0; s < 2; ++s) {
        FU hb0, hb1;
        hb0.u = *(const uint4*)&H[er][4*kb];
        hb1.u = *(const uint4*)&H[er][16 + 4*kb];
        #pragma unroll
        for (int ot = 0; ot < 4; ++ot) {
            FU a;
            a.u = *(const uint4*)(Wfs[s] + ((size_t)((l*4 + ot)*2 + 0)*64 + lane)*4);
            d[ot] = __builtin_amdgcn_mfma_f32_16x16x32_f16(a.h, hb0.h, zero4, 0, 0, 0);
            a.u = *(const uint4*)(Wfs[s] + ((size_t)((l*4 + ot)*2 + 1)*64 + lane)*4);
            d[ot] = __builtin_amdgcn_mfma_f32_16x16x32_f16(a.h, hb1.h, d[ot], 0, 0, 0);
        }
        #pragma unroll
        for (int ot = 0; ot < 4; ++ot) {
            uint p0 = pack2_f16(silu_f(d[ot][0]), silu_f(d[ot][1]));
            uint p1 = pack2_f16(silu_f(d[ot][2]), silu_f(d[ot][3]));
            uint* dst = &H[er][8*ot + 2*kb];
            dst[0] = p0; dst[1] = p1;
        }
    }

    // ---- stage 4: R = W4^T @ H; rank-interleaved staging; coalesced flush --
    FU hb0, hb1;
    hb0.u = *(const uint4*)&H[er][4*kb];
    hb1.u = *(const uint4*)&H[er][16 + 4*kb];
    #pragma unroll
    for (int ri = 0; ri < 4; ++ri) {
        #pragma unroll
        for (int otl = 0; otl < 4; ++otl) {
            int ot = ri*4 + otl;
            FU a;
            f32x4 d2;
            a.u = *(const uint4*)(Wf4 + ((size_t)((l*16 + ot)*2 + 0)*64 + lane)*4);
            d2 = __builtin_amdgcn_mfma_f32_16x16x32_f16(a.h, hb0.h, zero4, 0, 0, 0);
            a.u = *(const uint4*)(Wf4 + ((size_t)((l*16 + ot)*2 + 1)*64 + lane)*4);
            d2 = __builtin_amdgcn_mfma_f32_16x16x32_f16(a.h, hb1.h, d2, 0, 0, 0);
            int p = otl*8 + kb*2;
            H[er][(p  )*4 + ri] = pack2_f16(d2[0], d2[1]);
            H[er][(p+1)*4 + ri] = pack2_f16(d2[2], d2[3]);
        }
    }
    // flush 16 rows x 128 u32, coalesced
    #pragma unroll
    for (int it = 0; it < 8; ++it) {
        int f   = it*64 + lane;
        int row = f >> 5;
        int q4  = (f & 31) * 4;
        int eg  = e0 + row;
        if (eg < E)
            *(uint4*)(Rpk + ((size_t)l*E + eg)*128 + q4) = *(const uint4*)&H[row][q4];
    }
}

// ---------------- node gather + contraction + mix + readout ----------------
__global__ __launch_bounds__(256) void k_node(
    const uint*  __restrict__ Rpk,     // [E,128] u32 this layer (rank-interleaved)
    const float* __restrict__ h0,      // [N,64]
    const int*   __restrict__ senders, // [E]
    const float* __restrict__ rhat4,   // [E,4]
    const int*   __restrict__ offsets, // [N+1]
    const int*   __restrict__ elist,   // [E]
    const float* __restrict__ mixw,    // [4,64,64] (this layer)
    const float* __restrict__ readw,   // [64]      (this layer)
    float* __restrict__ h0n,           // [N,64]
    const float* __restrict__ eprev,   // [N] or null
    float* __restrict__ eout,          // [N]
    int N)
{
    int gtid = blockIdx.x * blockDim.x + threadIdx.x;
    int wave = gtid >> 6;
    int lane = threadIdx.x & 63;
    int w    = threadIdx.x >> 6;
    __shared__ float Bl[4][4][64];
    bool active = (wave < N);
    int n = active ? wave : 0;
    int half  = lane & 1;
    int cpair = lane >> 1;

    float a0 = 0.f;
    float a1[3]  = {0.f,0.f,0.f};
    float a2[6]  = {0.f,0.f,0.f,0.f,0.f,0.f};
    float a3[10] = {0.f,0.f,0.f,0.f,0.f,0.f,0.f,0.f,0.f,0.f};

    auto accum = [&](float x, float y, float z, float hj, uint4 qv) {
        float t0 = unpk_f16(qv.x, half) * hj;
        float t1 = unpk_f16(qv.y, half) * hj;
        float t2 = unpk_f16(qv.z, half) * hj;
        float t3 = unpk_f16(qv.w, half) * hj;
        a0 += t0;
        a1[0] = fmaf(t1, x, a1[0]);
        a1[1] = fmaf(t1, y, a1[1]);
        a1[2] = fmaf(t1, z, a1[2]);
        float qxx = x*x, qxy = x*y, qxz = x*z, qyy = y*y, qyz = y*z, qzz = z*z;
        a2[0] = fmaf(t2, qxx, a2[0]);
        a2[1] = fmaf(t2, qxy, a2[1]);
        a2[2] = fmaf(t2, qxz, a2[2]);
        a2[3] = fmaf(t2, qyy, a2[3]);
        a2[4] = fmaf(t2, qyz, a2[4]);
        a2[5] = fmaf(t2, qzz, a2[5]);
        float u0 = t3*qxx, u1 = t3*qxy, u3 = t3*qyy, u5 = t3*qzz;
        a3[0] = fmaf(u0, x, a3[0]);  // xxx
        a3[1] = fmaf(u0, y, a3[1]);  // xxy
        a3[2] = fmaf(u0, z, a3[2]);  // xxz
        a3[3] = fmaf(u3, x, a3[3]);  // xyy
        a3[4] = fmaf(u1, z, a3[4]);  // xyz
        a3[5] = fmaf(u5, x, a3[5]);  // xzz
        a3[6] = fmaf(u3, y, a3[6]);  // yyy
        a3[7] = fmaf(u3, z, a3[7]);  // yyz
        a3[8] = fmaf(u5, y, a3[8]);  // yzz
        a3[9] = fmaf(u5, z, a3[9]);  // zzz
    };

    if (active) {
        int beg = __builtin_amdgcn_readfirstlane(offsets[n]);
        int end = __builtin_amdgcn_readfirstlane(offsets[n+1]);
        int i = beg;
        for (; i + 4 <= end; i += 4) {
            int   e_[4], sn_[4];
            #pragma unroll
            for (int k = 0; k < 4; ++k) {
                e_[k]  = __builtin_amdgcn_readfirstlane(elist[i+k]);
                sn_[k] = __builtin_amdgcn_readfirstlane(senders[e_[k]]);
            }
            float4 rh_[4]; float hj_[4]; uint4 q_[4];
            #pragma unroll
            for (int k = 0; k < 4; ++k) {
                rh_[k] = *(const float4*)(rhat4 + (size_t)e_[k]*4);
                hj_[k] = h0[(size_t)sn_[k]*64 + lane];
                q_[k]  = *(const uint4*)(Rpk + (size_t)e_[k]*128 + cpair*4);
            }
            #pragma unroll
            for (int k = 0; k < 4; ++k)
                accum(rh_[k].x, rh_[k].y, rh_[k].z, hj_[k], q_[k]);
        }
        for (; i < end; ++i) {
            int e   = __builtin_amdgcn_readfirstlane(elist[i]);
            int snd = __builtin_amdgcn_readfirstlane(senders[e]);
            float4 rh = *(const float4*)(rhat4 + (size_t)e*4);
            float  hj = h0[(size_t)snd*64 + lane];
            uint4  qv = *(const uint4*)(Rpk + (size_t)e*128 + cpair*4);
            accum(rh.x, rh.y, rh.z, hj, qv);
        }
    }

    // invariants: B_r = (2r+1)/256 * sum over full tensor (multiplicity wts)
    float B0 = a0 * 0.0625f;                       // A0/16 (linear, rank 0)
    float s1 = a1[0]*a1[0] + a1[1]*a1[1] + a1[2]*a1[2];
    float B1 = s1 * (3.0f/256.0f);
    float s2 = a2[0]*a2[0] + a2[3]*a2[3] + a2[5]*a2[5]
             + 2.0f*(a2[1]*a2[1] + a2[2]*a2[2] + a2[4]*a2[4]);
    float B2 = s2 * (5.0f/256.0f);
    float s3 = a3[0]*a3[0] + a3[6]*a3[6] + a3[9]*a3[9]
             + 3.0f*(a3[1]*a3[1] + a3[2]*a3[2] + a3[3]*a3[3]
                   + a3[5]*a3[5] + a3[7]*a3[7] + a3[8]*a3[8])
             + 6.0f*a3[4]*a3[4];
    float B3 = s3 * (7.0f/256.0f);

    Bl[w][0][lane] = B0;
    Bl[w][1][lane] = B1;
    Bl[w][2][lane] = B2;
    Bl[w][3][lane] = B3;
    __syncthreads();

    if (active) {
        float acc = 0.0f;
        for (int ri = 0; ri < 4; ++ri) {
            #pragma unroll 8
            for (int j = 0; j < 64; ++j)
                acc = fmaf(Bl[w][ri][j], mixw[(ri*64 + j)*64 + lane], acc);
        }
        h0n[(size_t)n*64 + lane] = acc;

        float evl = acc * readw[lane];
        #pragma unroll
        for (int off = 1; off < 64; off <<= 1) evl += __shfl_xor(evl, off, 64);
        if (lane == 0) {
            float o = evl;
            if (eprev) o += eprev[n];
            eout[n] = o;
        }
    }
}

// ---------------------------------------------------------------------------
extern "C" void kernel_launch(void* const* d_in, const int* in_sizes, int n_in,
                              void* d_out, int out_size, void* d_ws, size_t ws_size,
                              hipStream_t stream)
{
    const int*   species   = (const int*)  d_in[0];
    const int*   senders   = (const int*)  d_in[1];
    const int*   receivers = (const int*)  d_in[2];
    const float* edge_vec  = (const float*)d_in[3];
    const float* embed_w   = (const float*)d_in[4];
    const float* rad_w1    = (const float*)d_in[5];
    const float* rad_w2    = (const float*)d_in[6];
    const float* rad_w3    = (const float*)d_in[7];
    const float* rad_w4    = (const float*)d_in[8];
    const float* mix_w     = (const float*)d_in[9];
    const float* read_w    = (const float*)d_in[10];

    int N = in_sizes[0];
    int E = in_sizes[1];
    float* out = (float*)d_out;

    char* ws = (char*)d_ws;
    size_t off = 0;
    auto alloc = [&](size_t bytes) -> char* {
        char* p = ws + off;
        off = (off + bytes + 255) & ~(size_t)255;
        return p;
    };
    uint*  rbh   = (uint*) alloc((size_t)E*4*sizeof(uint));
    float* rhat4 = (float*)alloc((size_t)E*4*sizeof(float));
    float* h0a   = (float*)alloc((size_t)N*64*sizeof(float));
    float* h0b   = (float*)alloc((size_t)N*64*sizeof(float));
    float* ener  = (float*)alloc((size_t)N*sizeof(float));
    int* counts  = (int*)alloc((size_t)N*sizeof(int));
    int* offsets = (int*)alloc((size_t)(N+1)*sizeof(int));
    int* cursor  = (int*)alloc((size_t)N*sizeof(int));
    int* elist   = (int*)alloc((size_t)E*sizeof(int));
    uint* Wf1    = (uint*)alloc(2048*sizeof(uint));
    uint* Wf2    = (uint*)alloc(4096*sizeof(uint));
    uint* Wf3    = (uint*)alloc(4096*sizeof(uint));
    uint* Wf4    = (uint*)alloc(16384*sizeof(uint));
    uint* Rpk    = (uint*)alloc((size_t)2*E*128*sizeof(uint));

    hipMemsetAsync(counts, 0, (size_t)N*sizeof(int), stream);
    hipMemsetAsync(cursor, 0, (size_t)N*sizeof(int), stream);

    k_edge_basis<<<(E + 255)/256, 256, 0, stream>>>(
        edge_vec, receivers, rbh, rhat4, counts, E);
    k_prep_w<<<(26624 + 255)/256, 256, 0, stream>>>(
        rad_w1, rad_w2, rad_w3, rad_w4, Wf1, Wf2, Wf3, Wf4);
    k_scan<<<1, 1024, 0, stream>>>(counts, offsets, N);
    k_scatter<<<(E + 255)/256, 256, 0, stream>>>(receivers, offsets, cursor, elist, E);
    k_sort_wave<<<((size_t)N*64 + 255)/256, 256, 0, stream>>>(offsets, elist, N);
    k_embed<<<((size_t)N*64 + 255)/256, 256, 0, stream>>>(species, embed_w, h0a, N*64);

    int tiles = (E + 15) / 16;
    int waves = 2 * tiles;
    k_mlp_mfma<<<(waves + 3)/4, 256, 0, stream>>>(
        rbh, Wf1, Wf2, Wf3, Wf4, Rpk, E, tiles);

    float* hcur = h0a;
    float* hnxt = h0b;
    for (int l = 0; l < 2; ++l) {
        uint* Rl = Rpk + (size_t)l * E * 128;
        k_node<<<((size_t)N*64 + 255)/256, 256, 0, stream>>>(
            Rl, hcur, senders, rhat4, offsets, elist,
            mix_w + (size_t)l*4*64*64,
            read_w + (size_t)l*64,
            hnxt,
            (l == 0) ? nullptr : ener,
            (l == 0) ? ener : out,
            N);
        float* tmp = hcur; hcur = hnxt; hnxt = tmp;
    }
}